// Round 4
// baseline (2998.876 us; speedup 1.0000x reference)
//
#include <hip/hip_runtime.h>
#include <hip/hip_cooperative_groups.h>
#include <math.h>

namespace cg = cooperative_groups;

// Problem constants
#define B_    32
#define CIN   4
#define SLEN  2048
#define NF    256
#define HD    256          // LSTM hidden per direction
#define SP    341          // post conv+pool sequence length
#define RTOT  (B_*SP)      // 10912 rows
#define NH_   8
#define DH_   64
#define GRP   4            // batches per attention group
#define PSTR  344          // padded P row stride (16B-aligned)
#define HS    (SP*HD)      // 87296: per-dir h elems

typedef __attribute__((ext_vector_type(8))) short short8;
typedef __attribute__((ext_vector_type(4))) float floatx4;
typedef __attribute__((ext_vector_type(4))) unsigned short ushortx4;
typedef __attribute__((ext_vector_type(8))) unsigned short ushort8;

__device__ __forceinline__ float sigmoidf_(float x) { return 1.0f / (1.0f + expf(-x)); }

__device__ __forceinline__ unsigned short f2bf(float x) {
    unsigned int u = __float_as_uint(x);
    unsigned int r = (u + 0x7FFF + ((u >> 16) & 1)) >> 16;   // RNE
    return (unsigned short)r;
}
__device__ __forceinline__ float bf2f(unsigned short b) {
    return __uint_as_float(((unsigned int)b) << 16);
}

// ---------------------------------------------------------------------------
// Packed bf16 hi/lo "octet" layout: for a row of K fp32 values, the packed row
// has 2K ushorts: octet o (elems 8o..8o+7) occupies ushorts [16o..16o+7]=hi,
// [16o+8..16o+15]=lo.  One K-step of 32 elems = 128 contiguous bytes.
// ---------------------------------------------------------------------------

// Kernel 1: Conv1d(4->256,k13,pad6)+BN+ReLU+MaxPool1d(6) -> x0 packed
__global__ __launch_bounds__(256)
void conv_pool_k(const float* __restrict__ in, const float* __restrict__ cw,
                 const float* __restrict__ gamma, const float* __restrict__ beta,
                 unsigned short* __restrict__ x0p)
{
    const int b  = blockIdx.y;
    const int s0 = blockIdx.x * 16;
    const int co = threadIdx.x;
    __shared__ float ins[CIN][16*6 + 12];
    for (int idx = threadIdx.x; idx < CIN*108; idx += 256) {
        int ci = idx / 108, o = idx % 108;
        int pos = 6*s0 - 6 + o;
        ins[ci][o] = (pos >= 0 && pos < SLEN) ? in[(b*CIN + ci)*SLEN + pos] : 0.0f;
    }
    float wreg[52];
    {
        const float4* wp = (const float4*)(cw + co*52);
        #pragma unroll
        for (int j4 = 0; j4 < 13; ++j4) {
            float4 w4 = wp[j4];
            wreg[j4*4+0]=w4.x; wreg[j4*4+1]=w4.y; wreg[j4*4+2]=w4.z; wreg[j4*4+3]=w4.w;
        }
    }
    const float scale = gamma[co] * (1.0f / sqrtf(1.0f + 1e-5f));
    const float shift = beta[co];
    __syncthreads();
    for (int si = 0; si < 16; ++si) {
        int s = s0 + si;
        if (s >= SP) break;
        float win[CIN][18];
        #pragma unroll
        for (int ci = 0; ci < CIN; ++ci)
            #pragma unroll
            for (int o = 0; o < 18; ++o)
                win[ci][o] = ins[ci][6*si + o];
        float m = -1e30f;
        #pragma unroll
        for (int p6 = 0; p6 < 6; ++p6) {
            float acc = 0.0f;
            #pragma unroll
            for (int ci = 0; ci < CIN; ++ci)
                #pragma unroll
                for (int kk = 0; kk < 13; ++kk)
                    acc += win[ci][p6+kk] * wreg[ci*13+kk];
            float val = acc * scale + shift;
            val = fmaxf(val, 0.0f);
            m = fmaxf(m, val);
        }
        unsigned short hb_ = f2bf(m);
        unsigned short lb_ = f2bf(m - bf2f(hb_));
        size_t rb = (size_t)(b*SP + s)*512 + (size_t)(co >> 3)*16 + (co & 7);
        x0p[rb]     = hb_;
        x0p[rb + 8] = lb_;
    }
}

// Kernel 2a: fp32 -> separate hi/lo pack (for lstm Whh, layout unchanged)
__global__ __launch_bounds__(256)
void pack4_k(const float* __restrict__ W, unsigned short* __restrict__ hi,
             unsigned short* __restrict__ lo, int n4)
{
    int i = blockIdx.x * 256 + threadIdx.x;
    if (i >= n4) return;
    float4 x = *((const float4*)W + i);
    float v[4] = {x.x, x.y, x.z, x.w};
    ushortx4 h, l;
    #pragma unroll
    for (int e = 0; e < 4; ++e) {
        unsigned short hb = f2bf(v[e]);
        h[e] = hb;
        l[e] = f2bf(v[e] - bf2f(hb));
    }
    *((ushortx4*)hi + i) = h;
    *((ushortx4*)lo + i) = l;
}

// Kernel 2b: fp32 -> interleaved octet pack (8 elems/thread)
__global__ __launch_bounds__(256)
void pack8_k(const float* __restrict__ W, unsigned short* __restrict__ O, int n8)
{
    int i = blockIdx.x * 256 + threadIdx.x;
    if (i >= n8) return;
    const float4* wp = (const float4*)W + (size_t)i*2;
    float4 a = wp[0], b = wp[1];
    float v[8] = {a.x,a.y,a.z,a.w,b.x,b.y,b.z,b.w};
    ushort8 h, l;
    #pragma unroll
    for (int e = 0; e < 8; ++e) {
        unsigned short hb = f2bf(v[e]);
        h[e] = hb;
        l[e] = f2bf(v[e] - bf2f(hb));
    }
    *(ushort8*)(O + (size_t)i*16)     = h;
    *(ushort8*)(O + (size_t)i*16 + 8) = l;
}

// ---------------------------------------------------------------------------
// Kernel 3: split-bf16 MFMA GEMM, operands in packed octet layout.
// C[M,N] = act(A[M,K] @ Bw[N,K]^T + bias).  Tile 128x128, 4 waves, K-step 32.
// Reg-staged: coalesced short8 global loads; LDS write at chunk lj^(row&7)
// (per-row permutation -> conflict-free writes); frag ds_read_b128 applies the
// same XOR -> 2 lanes/bank (free).  LDS 32 KB.
// ---------------------------------------------------------------------------
template<int RELU>
__global__ __launch_bounds__(256)
void gemm_bf_k(const unsigned short* __restrict__ Ap, const unsigned short* __restrict__ Bp,
               const float* __restrict__ bias, float* __restrict__ C,
               int M, int N, int K)
{
    const int n0 = blockIdx.x * 128;
    const int m0 = blockIdx.y * 128;
    const int tid = threadIdx.x;
    const int lane = tid & 63;
    const int w = tid >> 6;
    const int wm = w >> 1, wn = w & 1;          // wave 2x2 over the 128x128 tile
    const int ln15 = lane & 15, lq = lane >> 4;
    const int l8 = lane >> 3, lj = lane & 7;    // staging: row-in-group, chunk
    const size_t rstr = 2*(size_t)K;            // packed row stride (ushorts)

    __shared__ unsigned short As[128*64];       // 128 rows x 128B (one K-step)
    __shared__ unsigned short Bs[128*64];

    floatx4 acc[4][4];
    #pragma unroll
    for (int i = 0; i < 4; ++i)
        #pragma unroll
        for (int j = 0; j < 4; ++j) acc[i][j] = (floatx4){0.f, 0.f, 0.f, 0.f};

    // per-thread staging rows (4 for A, 4 for B) and swizzled LDS positions
    int rloc[4];
    #pragma unroll
    for (int c = 0; c < 4; ++c) rloc[c] = w*32 + c*8 + l8;
    const int spos = lj ^ (l8 & 7);             // row&7 == l8 for these rows

    for (int k0 = 0; k0 < K; k0 += 32) {
        short8 va[4], vb[4];
        #pragma unroll
        for (int c = 0; c < 4; ++c) {
            int gra = m0 + rloc[c]; if (gra >= M) gra = M - 1;
            va[c] = *(const short8*)(Ap + (size_t)gra*rstr + k0*2 + lj*8);
            vb[c] = *(const short8*)(Bp + (size_t)(n0 + rloc[c])*rstr + k0*2 + lj*8);
        }
        __syncthreads();   // previous iteration's LDS reads complete
        #pragma unroll
        for (int c = 0; c < 4; ++c) {
            *(short8*)&As[rloc[c]*64 + spos*8] = va[c];
            *(short8*)&Bs[rloc[c]*64 + spos*8] = vb[c];
        }
        __syncthreads();

        short8 fa_h[4], fa_l[4], fb_h[4], fb_l[4];
        #pragma unroll
        for (int mt = 0; mt < 4; ++mt) {
            const int lr = wm*64 + mt*16 + ln15;
            fa_h[mt] = *(const short8*)&As[lr*64 + (((lq*2  ) ^ (lr&7))*8)];
            fa_l[mt] = *(const short8*)&As[lr*64 + (((lq*2+1) ^ (lr&7))*8)];
        }
        #pragma unroll
        for (int nt = 0; nt < 4; ++nt) {
            const int lr = wn*64 + nt*16 + ln15;
            fb_h[nt] = *(const short8*)&Bs[lr*64 + (((lq*2  ) ^ (lr&7))*8)];
            fb_l[nt] = *(const short8*)&Bs[lr*64 + (((lq*2+1) ^ (lr&7))*8)];
        }
        #pragma unroll
        for (int mt = 0; mt < 4; ++mt)
            #pragma unroll
            for (int nt = 0; nt < 4; ++nt) {
                acc[mt][nt] = __builtin_amdgcn_mfma_f32_16x16x32_bf16(fa_l[mt], fb_h[nt], acc[mt][nt], 0, 0, 0);
                acc[mt][nt] = __builtin_amdgcn_mfma_f32_16x16x32_bf16(fa_h[mt], fb_l[nt], acc[mt][nt], 0, 0, 0);
                acc[mt][nt] = __builtin_amdgcn_mfma_f32_16x16x32_bf16(fa_h[mt], fb_h[nt], acc[mt][nt], 0, 0, 0);
            }
    }

    // epilogue: D layout n=lane&15 (col), m=(lane>>4)*4+r (row)
    #pragma unroll
    for (int nt = 0; nt < 4; ++nt) {
        const int n = n0 + wn*64 + nt*16 + ln15;
        const float bv = bias[n];
        #pragma unroll
        for (int mt = 0; mt < 4; ++mt) {
            const int mbase = m0 + wm*64 + mt*16 + lq*4;
            #pragma unroll
            for (int r = 0; r < 4; ++r) {
                int m = mbase + r;
                if (m < M) {
                    float val = acc[mt][nt][r] + bv;
                    if (RELU) val = fmaxf(val, 0.0f);
                    C[(size_t)m*N + n] = val;
                }
            }
        }
    }
}

// ---------------------------------------------------------------------------
// Kernel 3b: PERSISTENT cooperative LSTM scan — one launch per layer.
// Loops s=0..31 internally; grid.sync() between steps (176 blocks <= 256 CUs,
// co-resident by construction).  s==0 uses h=0 (skip recurrent MFMA) and c=0,
// eliminating the hb/cb memsets.  x_out written PACKED.
// ---------------------------------------------------------------------------
__global__ __launch_bounds__(256)
void lstm_scan_k(const float* __restrict__ G,              // [32*341][2048]
                 const unsigned short* __restrict__ Whi,   // [2][1024][256]
                 const unsigned short* __restrict__ Wlo,
                 float* __restrict__ hb,                   // [2][2*341*256] dbuf
                 float* __restrict__ c_st,                 // [2][341][256]
                 unsigned short* __restrict__ x_out)       // [32*341] packed rows of 512
{
    cg::grid_group grid = cg::this_grid();
    const int j0 = blockIdx.x * 32;
    const int m0 = blockIdx.y * 32;
    const int d  = blockIdx.z;
    const int tid = threadIdx.x;
    const int w = tid >> 6, lane = tid & 63;
    const int mhalf = w & 1, gpair = w >> 1;
    const int ln15 = lane & 15, lq = lane >> 4;
    const size_t hsz = (size_t)2*SP*HD;

    __shared__ float Csh[32][132];

    int am = m0 + mhalf*16 + ln15; if (am > SP-1) am = SP-1;   // A row (clamped)
    const int akoff = lq * 8;

    const unsigned short* WhiD = Whi + (size_t)d*1024*256;
    const unsigned short* WloD = Wlo + (size_t)d*1024*256;
    int nrow[4];   // Whh row (output col) per n-subtile
    #pragma unroll
    for (int t = 0; t < 4; ++t)
        nrow[t] = (gpair*2 + (t>>1))*256 + j0 + (t&1)*16 + ln15;

    const int emloc = tid >> 3;           // 0..31 local row
    const int ej4   = (tid & 7) * 4;      // 0..28 local col (x4)
    const int em    = m0 + emloc;

    for (int s = 0; s < B_; ++s) {
        const int t_in = d ? (B_ - 1 - s) : s;
        const float* hA = hb + (size_t)(s & 1)*hsz + (size_t)d*HS + (size_t)am*HD;
        float* h_out = hb + (size_t)((s+1) & 1)*hsz;

        floatx4 acc[4];
        #pragma unroll
        for (int t = 0; t < 4; ++t) acc[t] = (floatx4){0.f, 0.f, 0.f, 0.f};

        if (s > 0) {
            #pragma unroll
            for (int kk = 0; kk < 8; ++kk) {
                const int ko = kk*32 + akoff;
                float4 v0 = *(const float4*)(hA + ko);
                float4 v1 = *(const float4*)(hA + ko + 4);
                float vv[8] = {v0.x, v0.y, v0.z, v0.w, v1.x, v1.y, v1.z, v1.w};
                short8 ahi, alo;
                #pragma unroll
                for (int e = 0; e < 8; ++e) {
                    unsigned short hb16 = f2bf(vv[e]);
                    ahi[e] = (short)hb16;
                    alo[e] = (short)f2bf(vv[e] - bf2f(hb16));
                }
                #pragma unroll
                for (int t = 0; t < 4; ++t) {
                    short8 bhi = *(const short8*)(WhiD + (size_t)nrow[t]*HD + ko);
                    short8 blo = *(const short8*)(WloD + (size_t)nrow[t]*HD + ko);
                    acc[t] = __builtin_amdgcn_mfma_f32_16x16x32_bf16(alo, bhi, acc[t], 0, 0, 0);
                    acc[t] = __builtin_amdgcn_mfma_f32_16x16x32_bf16(ahi, blo, acc[t], 0, 0, 0);
                    acc[t] = __builtin_amdgcn_mfma_f32_16x16x32_bf16(ahi, bhi, acc[t], 0, 0, 0);
                }
            }
        }

        // dump C fragments to LDS (D: col=lane&15, row=lq*4+reg)
        #pragma unroll
        for (int t = 0; t < 4; ++t) {
            int col = gpair*64 + (t>>1)*32 + (t&1)*16 + ln15;
            int rb  = mhalf*16 + lq*4;
            #pragma unroll
            for (int r = 0; r < 4; ++r)
                Csh[rb + r][col] = acc[t][r];
        }
        __syncthreads();

        if (em < SP) {
            size_t gb = ((size_t)t_in*SP + em)*2048 + (size_t)d*1024 + j0 + ej4;
            float4 gi4 = *(const float4*)&G[gb];
            float4 gf4 = *(const float4*)&G[gb + 256];
            float4 gg4 = *(const float4*)&G[gb + 512];
            float4 go4 = *(const float4*)&G[gb + 768];
            size_t cbase = ((size_t)d*SP + em)*HD + j0 + ej4;
            float4 cold;
            if (s > 0) cold = *(float4*)&c_st[cbase];
            else       cold = (float4){0.f, 0.f, 0.f, 0.f};
            float hv[4];
            #pragma unroll
            for (int e = 0; e < 4; ++e) {
                float gi = Csh[emloc][     ej4+e] + (&gi4.x)[e];
                float gf = Csh[emloc][32 + ej4+e] + (&gf4.x)[e];
                float gg = Csh[emloc][64 + ej4+e] + (&gg4.x)[e];
                float go = Csh[emloc][96 + ej4+e] + (&go4.x)[e];
                float cn = sigmoidf_(gf)*(&cold.x)[e] + sigmoidf_(gi)*tanhf(gg);
                (&cold.x)[e] = cn;
                hv[e] = sigmoidf_(go)*tanhf(cn);
            }
            *(float4*)&c_st[cbase] = cold;
            float4 ho; ho.x = hv[0]; ho.y = hv[1]; ho.z = hv[2]; ho.w = hv[3];
            *(float4*)&h_out[cbase] = ho;
            // packed x_out write
            const int colg = d*HD + j0 + ej4;
            size_t xb = ((size_t)t_in*SP + em)*1024 + (size_t)(colg >> 3)*16 + (colg & 7);
            ushortx4 xh, xl;
            #pragma unroll
            for (int e = 0; e < 4; ++e) {
                unsigned short hb16 = f2bf(hv[e]);
                xh[e] = hb16;
                xl[e] = f2bf(hv[e] - bf2f(hb16));
            }
            *(ushortx4*)&x_out[xb]     = xh;
            *(ushortx4*)&x_out[xb + 8] = xl;
        }
        grid.sync();   // h/c visible device-wide; Csh safe to overwrite
    }
}

// ---------------------------------------------------------------------------
// Kernel 4a: scores tile (64x64), RPE analytic.
// ---------------------------------------------------------------------------
__global__ __launch_bounds__(256)
void scores_k(const float* __restrict__ q, const float* __restrict__ k,
              float* __restrict__ P, int g)
{
    const int h = blockIdx.z, bl = blockIdx.y, bg = g*GRP + bl;
    const int q0 = (blockIdx.x / 6) * 64;
    const int k0 = (blockIdx.x % 6) * 64;
    const int tid = threadIdx.x;
    __shared__ float qs[64][68];
    __shared__ float ks[64][68];
    {
        int jr = tid >> 2, c16 = (tid & 3) * 16;
        int qq = q0 + jr; if (qq > SP-1) qq = SP-1;
        int kr = k0 + jr; if (kr > SP-1) kr = SP-1;
        const float* qp = &q[((size_t)bg*SP + qq)*512 + h*64 + c16];
        const float* kp = &k[((size_t)bg*SP + kr)*512 + h*64 + c16];
        #pragma unroll
        for (int u = 0; u < 4; ++u) {
            *(float4*)&qs[jr][c16 + u*4] = *(const float4*)(qp + u*4);
            *(float4*)&ks[jr][c16 + u*4] = *(const float4*)(kp + u*4);
        }
    }
    __syncthreads();
    const int tx = tid & 15, ty = tid >> 4;
    float acc[4][4];
    #pragma unroll
    for (int i = 0; i < 4; ++i)
        #pragma unroll
        for (int j = 0; j < 4; ++j) acc[i][j] = 0.0f;
    for (int d4 = 0; d4 < 64; d4 += 4) {
        float4 a[4], b[4];
        #pragma unroll
        for (int i = 0; i < 4; ++i) a[i] = *(const float4*)&qs[ty + 16*i][d4];
        #pragma unroll
        for (int j = 0; j < 4; ++j) b[j] = *(const float4*)&ks[tx + 16*j][d4];
        #pragma unroll
        for (int i = 0; i < 4; ++i)
            #pragma unroll
            for (int j = 0; j < 4; ++j)
                acc[i][j] += a[i].x*b[j].x + a[i].y*b[j].y + a[i].z*b[j].z + a[i].w*b[j].w;
    }
    #pragma unroll
    for (int i = 0; i < 4; ++i) {
        int qq = q0 + ty + 16*i;
        if (qq >= SP) continue;
        int r0 = 6*qq - 1; if (r0 < 0) r0 = 0;
        int r1 = 6*qq + 7; if (r1 > SLEN-1) r1 = SLEN-1;
        size_t rowb = ((size_t)(h*GRP + bl)*SP + qq) * PSTR;
        #pragma unroll
        for (int j = 0; j < 4; ++j) {
            int kk = k0 + tx + 16*j;
            if (kk >= SP) continue;
            int c0 = 6*kk - 1; if (c0 < 0) c0 = 0;
            int c1 = 6*kk + 7;
            int dd1 = c1 - r0; if (dd1 < 0) dd1 = -dd1;
            int dd2 = r1 - c0; if (dd2 < 0) dd2 = -dd2;
            int den = dd1 > dd2 ? dd1 : dd2;
            P[rowb + kk] = (acc[i][j] * 0.125f) * 2047.0f / (float)den;
        }
    }
}

// ---------------------------------------------------------------------------
// Kernel 4b: row softmax in place.
// ---------------------------------------------------------------------------
__global__ __launch_bounds__(256)
void softmax_k(float* __restrict__ P)
{
    const int tid = threadIdx.x;
    const int row = blockIdx.x * 4 + (tid >> 6);
    const int lane = tid & 63;
    float* rp = P + (size_t)row * PSTR;
    float v[6];
    float m = -1e30f;
    #pragma unroll
    for (int i = 0; i < 6; ++i) {
        int col = lane + 64*i;
        v[i] = (col < SP) ? rp[col] : -1e30f;
        m = fmaxf(m, v[i]);
    }
    #pragma unroll
    for (int o = 1; o < 64; o <<= 1) m = fmaxf(m, __shfl_xor(m, o, 64));
    float s = 0.0f;
    #pragma unroll
    for (int i = 0; i < 6; ++i) {
        v[i] = expf(v[i] - m);
        s += v[i];
    }
    #pragma unroll
    for (int o = 1; o < 64; o <<= 1) s += __shfl_xor(s, o, 64);
    float inv = 1.0f / s;
    #pragma unroll
    for (int i = 0; i < 6; ++i) {
        int col = lane + 64*i;
        if (col < SP) rp[col] = v[i] * inv;
    }
}

// ---------------------------------------------------------------------------
// Kernel 4c: out = relu(P @ V), K=SP in 6x64 chunks. cat written PACKED.
// ---------------------------------------------------------------------------
__global__ __launch_bounds__(256)
void pv_k(const float* __restrict__ P, const float* __restrict__ v,
          unsigned short* __restrict__ catp, int g)
{
    const int h = blockIdx.z, bl = blockIdx.y, bg = g*GRP + bl;
    const int q0 = blockIdx.x * 64;
    const int tid = threadIdx.x;
    __shared__ float ps[64][68];
    __shared__ float vs[64][68];
    const int tx = tid & 15, ty = tid >> 4;
    float acc[4][4];
    #pragma unroll
    for (int i = 0; i < 4; ++i)
        #pragma unroll
        for (int j = 0; j < 4; ++j) acc[i][j] = 0.0f;

    for (int kc = 0; kc < 6; ++kc) {
        const int kk0 = kc * 64;
        {
            int jr = tid >> 2, c16 = (tid & 3) * 16;
            int qq = q0 + jr; if (qq > SP-1) qq = SP-1;
            const float* pp = P + ((size_t)(h*GRP + bl)*SP + qq)*PSTR + kk0 + c16;
            #pragma unroll
            for (int u = 0; u < 4; ++u) {
                float4 w = *(const float4*)(pp + u*4);
                int klb = c16 + u*4;
                float vals[4] = {w.x, w.y, w.z, w.w};
                #pragma unroll
                for (int e = 0; e < 4; ++e)
                    ps[klb + e][jr] = (kk0 + klb + e < SP) ? vals[e] : 0.0f;
            }
        }
        {
            int jr = tid >> 2, c16 = (tid & 3) * 16;
            int kr = kk0 + jr; if (kr > SP-1) kr = SP-1;
            const float* vp = &v[((size_t)bg*SP + kr)*512 + h*64 + c16];
            #pragma unroll
            for (int u = 0; u < 4; ++u)
                *(float4*)&vs[jr][c16 + u*4] = *(const float4*)(vp + u*4);
        }
        __syncthreads();
        for (int kk = 0; kk < 64; ++kk) {
            float4 a4 = *(const float4*)&ps[kk][ty*4];
            float4 b4 = *(const float4*)&vs[kk][tx*4];
            float av[4] = {a4.x, a4.y, a4.z, a4.w};
            float bv[4] = {b4.x, b4.y, b4.z, b4.w};
            #pragma unroll
            for (int i = 0; i < 4; ++i)
                #pragma unroll
                for (int j = 0; j < 4; ++j)
                    acc[i][j] += av[i] * bv[j];
        }
        __syncthreads();
    }
    #pragma unroll
    for (int i = 0; i < 4; ++i) {
        int qq = q0 + ty*4 + i;
        if (qq >= SP) continue;
        float r[4];
        r[0] = fmaxf(acc[i][0], 0.0f);
        r[1] = fmaxf(acc[i][1], 0.0f);
        r[2] = fmaxf(acc[i][2], 0.0f);
        r[3] = fmaxf(acc[i][3], 0.0f);
        const int colg = h*64 + tx*4;
        size_t xb = ((size_t)bg*SP + qq)*1024 + (size_t)(colg >> 3)*16 + (colg & 7);
        ushortx4 xh, xl;
        #pragma unroll
        for (int e = 0; e < 4; ++e) {
            unsigned short hb16 = f2bf(r[e]);
            xh[e] = hb16;
            xl[e] = f2bf(r[e] - bf2f(hb16));
        }
        *(ushortx4*)&catp[xb]     = xh;
        *(ushortx4*)&catp[xb + 8] = xl;
    }
}

// ---------------------------------------------------------------------------
extern "C" void kernel_launch(void* const* d_in, const int* in_sizes, int n_in,
                              void* d_out, int out_size, void* d_ws, size_t ws_size,
                              hipStream_t stream)
{
    (void)in_sizes; (void)n_in; (void)out_size; (void)ws_size;
    const float* in    = (const float*)d_in[0];
    const float* cw    = (const float*)d_in[1];
    const float* gamma = (const float*)d_in[2];
    const float* beta  = (const float*)d_in[3];
    const float* Wih0  = (const float*)d_in[4];
    const float* Whh0  = (const float*)d_in[5];
    const float* b0    = (const float*)d_in[6];
    const float* Wih1  = (const float*)d_in[7];
    const float* Whh1  = (const float*)d_in[8];
    const float* b1    = (const float*)d_in[9];
    const float* Qw    = (const float*)d_in[10];
    const float* Qb    = (const float*)d_in[11];
    const float* Kw    = (const float*)d_in[12];
    const float* Kb    = (const float*)d_in[13];
    const float* Vw    = (const float*)d_in[14];
    const float* Vb    = (const float*)d_in[15];
    const float* mhw   = (const float*)d_in[16];
    const float* mhb   = (const float*)d_in[17];
    float* out = (float*)d_out;

    // workspace arena (floats). Same region map as before.
    float* x0 = (float*)d_ws;                                   //  2,793,472 f
    float* G  = x0 + (size_t)RTOT*NF;                           // 22,347,776 f
    float* x1 = G  + (size_t)RTOT*2048;                         //  5,586,944 f
    float* x2 = x1 + (size_t)RTOT*512;                          //  5,586,944 f
    float* hb = x2 + (size_t)RTOT*512;                          //    349,184 f
    float* cb = hb + (size_t)2*2*SP*HD;                         //    174,592 f

    float* qbuf = G;
    float* kbuf = G + (size_t)RTOT*512;
    float* vbuf = G + (size_t)2*RTOT*512;
    float* P    = G + (size_t)3*RTOT*512;

    // ---- packed-buffer aliases (each placed in a region dead at time of use) ----
    unsigned short* x0p = (unsigned short*)x0;
    unsigned short* whh1_hi = (unsigned short*)x0;                         // after gemm1
    unsigned short* whh1_lo = whh1_hi + (size_t)524288;
    unsigned short* wih0_p  = (unsigned short*)x2;
    unsigned short* wih1_p  = wih0_p + (size_t)1048576;
    unsigned short* whh0_hi = wih1_p + (size_t)2097152;
    unsigned short* whh0_lo = whh0_hi + (size_t)524288;
    unsigned short* x1p  = (unsigned short*)x1;
    unsigned short* catp = (unsigned short*)x1;
    unsigned short* x2p = (unsigned short*)x2;
    float* gslack = P + (size_t)NH_*GRP*SP*PSTR;
    unsigned short* qw_p = (unsigned short*)gslack;
    unsigned short* kw_p = qw_p + (size_t)524288;
    unsigned short* vw_p = kw_p + (size_t)524288;
    unsigned short* mw_p = vw_p + (size_t)524288;

    #define PACKGRID(n) dim3(((n) + 255) / 256)

    // 1. conv+bn+relu+pool -> x0p (packed)
    conv_pool_k<<<dim3(22, B_), 256, 0, stream>>>(in, cw, gamma, beta, x0p);
    // 2. pack Wih0 (octet) into x2 region
    pack8_k<<<PACKGRID(65536), 256, 0, stream>>>(Wih0, wih0_p, 65536);
    // 3. layer-1 input gates: G = x0 @ Wih0^T + b0   (K=256)
    gemm_bf_k<0><<<dim3(16, 86), 256, 0, stream>>>(x0p, wih0_p, b0, G, RTOT, 2048, 256);
    // 4. pack Whh0 (x2 tail), Whh1 (x0 region, dead after gemm1), Wih1 (x2)
    pack4_k<<<PACKGRID(131072), 256, 0, stream>>>(Whh0, whh0_hi, whh0_lo, 131072);
    pack4_k<<<PACKGRID(131072), 256, 0, stream>>>(Whh1, whh1_hi, whh1_lo, 131072);
    pack8_k<<<PACKGRID(131072), 256, 0, stream>>>(Wih1, wih1_p, 131072);
    // 5. layer-1 scan -> x1p (packed): single cooperative persistent kernel
    {
        const float* a0 = G; const unsigned short* a1 = whh0_hi; const unsigned short* a2 = whh0_lo;
        float* a3 = hb; float* a4 = cb; unsigned short* a5 = x1p;
        void* kargs[] = {&a0, &a1, &a2, &a3, &a4, &a5};
        hipLaunchCooperativeKernel((void*)lstm_scan_k, dim3(8, 11, 2), dim3(256, 1, 1), kargs, 0, stream);
    }
    // 6. layer-2 input gates: G = x1 @ Wih1^T + b1   (K=512)
    gemm_bf_k<0><<<dim3(16, 86), 256, 0, stream>>>(x1p, wih1_p, b1, G, RTOT, 2048, 512);
    // 7. layer-2 scan -> x2p (packed; overwrites x2-region weight packs, all dead)
    {
        const float* a0 = G; const unsigned short* a1 = whh1_hi; const unsigned short* a2 = whh1_lo;
        float* a3 = hb; float* a4 = cb; unsigned short* a5 = x2p;
        void* kargs[] = {&a0, &a1, &a2, &a3, &a4, &a5};
        hipLaunchCooperativeKernel((void*)lstm_scan_k, dim3(8, 11, 2), dim3(256, 1, 1), kargs, 0, stream);
    }
    // 8. pack QKV/mh weights into G tail slack (G-as-gates dead)
    pack8_k<<<PACKGRID(32768), 256, 0, stream>>>(Qw,  qw_p, 32768);
    pack8_k<<<PACKGRID(32768), 256, 0, stream>>>(Kw,  kw_p, 32768);
    pack8_k<<<PACKGRID(32768), 256, 0, stream>>>(Vw,  vw_p, 32768);
    pack8_k<<<PACKGRID(32768), 256, 0, stream>>>(mhw, mw_p, 32768);
    // 9. Q/K/V projections (fp32 outputs into G region)
    gemm_bf_k<0><<<dim3(4, 86), 256, 0, stream>>>(x2p, qw_p, Qb, qbuf, RTOT, 512, 512);
    gemm_bf_k<0><<<dim3(4, 86), 256, 0, stream>>>(x2p, kw_p, Kb, kbuf, RTOT, 512, 512);
    gemm_bf_k<0><<<dim3(4, 86), 256, 0, stream>>>(x2p, vw_p, Vb, vbuf, RTOT, 512, 512);
    // 10. attention in GRP-batch groups; pv writes catp (x1 region, packed)
    for (int g = 0; g < B_/GRP; ++g) {
        scores_k <<<dim3(36, GRP, NH_), 256, 0, stream>>>(qbuf, kbuf, P, g);
        softmax_k<<<dim3(NH_*GRP*SP/4), 256, 0, stream>>>(P);
        pv_k     <<<dim3(6, GRP, NH_), 256, 0, stream>>>(P, vbuf, catp, g);
    }
    // 11. final linear + relu
    gemm_bf_k<1><<<dim3(4, 86), 256, 0, stream>>>(catp, mw_p, mhb, out, RTOT, 512, 512);
    #undef PACKGRID
}

// Round 5
// 1908.126 us; speedup vs baseline: 1.5716x; 1.5716x over previous
//
#include <hip/hip_runtime.h>
#include <math.h>

// Problem constants
#define B_    32
#define CIN   4
#define SLEN  2048
#define NF    256
#define HD    256          // LSTM hidden per direction
#define SP    341          // post conv+pool sequence length
#define RTOT  (B_*SP)      // 10912 rows
#define NH_   8
#define DH_   64
#define GRP   4            // batches per attention group
#define PSTR  344          // padded P row stride (16B-aligned)
#define HS    (SP*HD)      // 87296: per-dir h elems
#define NBLK  176          // scan grid: 8 x 11 x 2

typedef __attribute__((ext_vector_type(8))) short short8;
typedef __attribute__((ext_vector_type(4))) float floatx4;
typedef __attribute__((ext_vector_type(4))) unsigned short ushortx4;
typedef __attribute__((ext_vector_type(8))) unsigned short ushort8;

__device__ __forceinline__ float sigmoidf_(float x) { return 1.0f / (1.0f + expf(-x)); }

__device__ __forceinline__ unsigned short f2bf(float x) {
    unsigned int u = __float_as_uint(x);
    unsigned int r = (u + 0x7FFF + ((u >> 16) & 1)) >> 16;   // RNE
    return (unsigned short)r;
}
__device__ __forceinline__ float bf2f(unsigned short b) {
    return __uint_as_float(((unsigned int)b) << 16);
}

// ---- LLC-coherent (Infinity Cache) access helpers: sc0 sc1 bypass L1/L2 ----
__device__ __forceinline__ void store_f4_llc(float* p, floatx4 v)
{
    asm volatile("global_store_dwordx4 %0, %1, off sc0 sc1" :: "v"(p), "v"(v) : "memory");
}
__device__ __forceinline__ unsigned load_u32_llc(const unsigned* p)
{
    unsigned r;
    asm volatile("global_load_dword %0, %1, off sc0 sc1\n\ts_waitcnt vmcnt(0)"
                 : "=v"(r) : "v"(p) : "memory");
    return r;
}
// 16 x dwordx4 from one base (offsets kk*128 and kk*128+16), single trailing
// waitcnt INSIDE the asm so no use can be scheduled before data lands.
__device__ __forceinline__ void load_h16_llc(const float* p, floatx4* r)
{
    asm volatile(
        "global_load_dwordx4 %0, %16, off sc0 sc1\n\t"
        "global_load_dwordx4 %1, %16, off offset:16 sc0 sc1\n\t"
        "global_load_dwordx4 %2, %16, off offset:128 sc0 sc1\n\t"
        "global_load_dwordx4 %3, %16, off offset:144 sc0 sc1\n\t"
        "global_load_dwordx4 %4, %16, off offset:256 sc0 sc1\n\t"
        "global_load_dwordx4 %5, %16, off offset:272 sc0 sc1\n\t"
        "global_load_dwordx4 %6, %16, off offset:384 sc0 sc1\n\t"
        "global_load_dwordx4 %7, %16, off offset:400 sc0 sc1\n\t"
        "global_load_dwordx4 %8, %16, off offset:512 sc0 sc1\n\t"
        "global_load_dwordx4 %9, %16, off offset:528 sc0 sc1\n\t"
        "global_load_dwordx4 %10, %16, off offset:640 sc0 sc1\n\t"
        "global_load_dwordx4 %11, %16, off offset:656 sc0 sc1\n\t"
        "global_load_dwordx4 %12, %16, off offset:768 sc0 sc1\n\t"
        "global_load_dwordx4 %13, %16, off offset:784 sc0 sc1\n\t"
        "global_load_dwordx4 %14, %16, off offset:896 sc0 sc1\n\t"
        "global_load_dwordx4 %15, %16, off offset:912 sc0 sc1\n\t"
        "s_waitcnt vmcnt(0)"
        : "=&v"(r[0]), "=&v"(r[1]), "=&v"(r[2]), "=&v"(r[3]),
          "=&v"(r[4]), "=&v"(r[5]), "=&v"(r[6]), "=&v"(r[7]),
          "=&v"(r[8]), "=&v"(r[9]), "=&v"(r[10]), "=&v"(r[11]),
          "=&v"(r[12]), "=&v"(r[13]), "=&v"(r[14]), "=&v"(r[15])
        : "v"(p)
        : "memory");
}

// ---------------------------------------------------------------------------
// Packed bf16 hi/lo "octet" layout: for a row of K fp32 values, the packed row
// has 2K ushorts: octet o (elems 8o..8o+7) occupies ushorts [16o..16o+7]=hi,
// [16o+8..16o+15]=lo.  One K-step of 32 elems = 128 contiguous bytes.
// ---------------------------------------------------------------------------

// Kernel 1: Conv1d(4->256,k13,pad6)+BN+ReLU+MaxPool1d(6) -> x0 packed
__global__ __launch_bounds__(256)
void conv_pool_k(const float* __restrict__ in, const float* __restrict__ cw,
                 const float* __restrict__ gamma, const float* __restrict__ beta,
                 unsigned short* __restrict__ x0p)
{
    const int b  = blockIdx.y;
    const int s0 = blockIdx.x * 16;
    const int co = threadIdx.x;
    __shared__ float ins[CIN][16*6 + 12];
    for (int idx = threadIdx.x; idx < CIN*108; idx += 256) {
        int ci = idx / 108, o = idx % 108;
        int pos = 6*s0 - 6 + o;
        ins[ci][o] = (pos >= 0 && pos < SLEN) ? in[(b*CIN + ci)*SLEN + pos] : 0.0f;
    }
    float wreg[52];
    {
        const float4* wp = (const float4*)(cw + co*52);
        #pragma unroll
        for (int j4 = 0; j4 < 13; ++j4) {
            float4 w4 = wp[j4];
            wreg[j4*4+0]=w4.x; wreg[j4*4+1]=w4.y; wreg[j4*4+2]=w4.z; wreg[j4*4+3]=w4.w;
        }
    }
    const float scale = gamma[co] * (1.0f / sqrtf(1.0f + 1e-5f));
    const float shift = beta[co];
    __syncthreads();
    for (int si = 0; si < 16; ++si) {
        int s = s0 + si;
        if (s >= SP) break;
        float win[CIN][18];
        #pragma unroll
        for (int ci = 0; ci < CIN; ++ci)
            #pragma unroll
            for (int o = 0; o < 18; ++o)
                win[ci][o] = ins[ci][6*si + o];
        float m = -1e30f;
        #pragma unroll
        for (int p6 = 0; p6 < 6; ++p6) {
            float acc = 0.0f;
            #pragma unroll
            for (int ci = 0; ci < CIN; ++ci)
                #pragma unroll
                for (int kk = 0; kk < 13; ++kk)
                    acc += win[ci][p6+kk] * wreg[ci*13+kk];
            float val = acc * scale + shift;
            val = fmaxf(val, 0.0f);
            m = fmaxf(m, val);
        }
        unsigned short hb_ = f2bf(m);
        unsigned short lb_ = f2bf(m - bf2f(hb_));
        size_t rb = (size_t)(b*SP + s)*512 + (size_t)(co >> 3)*16 + (co & 7);
        x0p[rb]     = hb_;
        x0p[rb + 8] = lb_;
    }
}

// Kernel 2a: fp32 -> separate hi/lo pack (for lstm Whh, layout unchanged)
__global__ __launch_bounds__(256)
void pack4_k(const float* __restrict__ W, unsigned short* __restrict__ hi,
             unsigned short* __restrict__ lo, int n4)
{
    int i = blockIdx.x * 256 + threadIdx.x;
    if (i >= n4) return;
    float4 x = *((const float4*)W + i);
    float v[4] = {x.x, x.y, x.z, x.w};
    ushortx4 h, l;
    #pragma unroll
    for (int e = 0; e < 4; ++e) {
        unsigned short hb = f2bf(v[e]);
        h[e] = hb;
        l[e] = f2bf(v[e] - bf2f(hb));
    }
    *((ushortx4*)hi + i) = h;
    *((ushortx4*)lo + i) = l;
}

// Kernel 2b: fp32 -> interleaved octet pack (8 elems/thread)
__global__ __launch_bounds__(256)
void pack8_k(const float* __restrict__ W, unsigned short* __restrict__ O, int n8)
{
    int i = blockIdx.x * 256 + threadIdx.x;
    if (i >= n8) return;
    const float4* wp = (const float4*)W + (size_t)i*2;
    float4 a = wp[0], b = wp[1];
    float v[8] = {a.x,a.y,a.z,a.w,b.x,b.y,b.z,b.w};
    ushort8 h, l;
    #pragma unroll
    for (int e = 0; e < 8; ++e) {
        unsigned short hb = f2bf(v[e]);
        h[e] = hb;
        l[e] = f2bf(v[e] - bf2f(hb));
    }
    *(ushort8*)(O + (size_t)i*16)     = h;
    *(ushort8*)(O + (size_t)i*16 + 8) = l;
}

// ---------------------------------------------------------------------------
// Kernel 3: split-bf16 MFMA GEMM, operands in packed octet layout.
// (unchanged from round 3)
// ---------------------------------------------------------------------------
template<int RELU>
__global__ __launch_bounds__(256)
void gemm_bf_k(const unsigned short* __restrict__ Ap, const unsigned short* __restrict__ Bp,
               const float* __restrict__ bias, float* __restrict__ C,
               int M, int N, int K)
{
    const int n0 = blockIdx.x * 128;
    const int m0 = blockIdx.y * 128;
    const int tid = threadIdx.x;
    const int lane = tid & 63;
    const int w = tid >> 6;
    const int wm = w >> 1, wn = w & 1;
    const int ln15 = lane & 15, lq = lane >> 4;
    const int l8 = lane >> 3, lj = lane & 7;
    const size_t rstr = 2*(size_t)K;

    __shared__ unsigned short As[128*64];
    __shared__ unsigned short Bs[128*64];

    floatx4 acc[4][4];
    #pragma unroll
    for (int i = 0; i < 4; ++i)
        #pragma unroll
        for (int j = 0; j < 4; ++j) acc[i][j] = (floatx4){0.f, 0.f, 0.f, 0.f};

    int rloc[4];
    #pragma unroll
    for (int c = 0; c < 4; ++c) rloc[c] = w*32 + c*8 + l8;
    const int spos = lj ^ (l8 & 7);

    for (int k0 = 0; k0 < K; k0 += 32) {
        short8 va[4], vb[4];
        #pragma unroll
        for (int c = 0; c < 4; ++c) {
            int gra = m0 + rloc[c]; if (gra >= M) gra = M - 1;
            va[c] = *(const short8*)(Ap + (size_t)gra*rstr + k0*2 + lj*8);
            vb[c] = *(const short8*)(Bp + (size_t)(n0 + rloc[c])*rstr + k0*2 + lj*8);
        }
        __syncthreads();
        #pragma unroll
        for (int c = 0; c < 4; ++c) {
            *(short8*)&As[rloc[c]*64 + spos*8] = va[c];
            *(short8*)&Bs[rloc[c]*64 + spos*8] = vb[c];
        }
        __syncthreads();

        short8 fa_h[4], fa_l[4], fb_h[4], fb_l[4];
        #pragma unroll
        for (int mt = 0; mt < 4; ++mt) {
            const int lr = wm*64 + mt*16 + ln15;
            fa_h[mt] = *(const short8*)&As[lr*64 + (((lq*2  ) ^ (lr&7))*8)];
            fa_l[mt] = *(const short8*)&As[lr*64 + (((lq*2+1) ^ (lr&7))*8)];
        }
        #pragma unroll
        for (int nt = 0; nt < 4; ++nt) {
            const int lr = wn*64 + nt*16 + ln15;
            fb_h[nt] = *(const short8*)&Bs[lr*64 + (((lq*2  ) ^ (lr&7))*8)];
            fb_l[nt] = *(const short8*)&Bs[lr*64 + (((lq*2+1) ^ (lr&7))*8)];
        }
        #pragma unroll
        for (int mt = 0; mt < 4; ++mt)
            #pragma unroll
            for (int nt = 0; nt < 4; ++nt) {
                acc[mt][nt] = __builtin_amdgcn_mfma_f32_16x16x32_bf16(fa_l[mt], fb_h[nt], acc[mt][nt], 0, 0, 0);
                acc[mt][nt] = __builtin_amdgcn_mfma_f32_16x16x32_bf16(fa_h[mt], fb_l[nt], acc[mt][nt], 0, 0, 0);
                acc[mt][nt] = __builtin_amdgcn_mfma_f32_16x16x32_bf16(fa_h[mt], fb_h[nt], acc[mt][nt], 0, 0, 0);
            }
    }

    #pragma unroll
    for (int nt = 0; nt < 4; ++nt) {
        const int n = n0 + wn*64 + nt*16 + ln15;
        const float bv = bias[n];
        #pragma unroll
        for (int mt = 0; mt < 4; ++mt) {
            const int mbase = m0 + wm*64 + mt*16 + lq*4;
            #pragma unroll
            for (int r = 0; r < 4; ++r) {
                int m = mbase + r;
                if (m < M) {
                    float val = acc[mt][nt][r] + bv;
                    if (RELU) val = fmaxf(val, 0.0f);
                    C[(size_t)m*N + n] = val;
                }
            }
        }
    }
}

// ---------------------------------------------------------------------------
// Kernel 3b: PERSISTENT LSTM scan with custom LLC barrier.
// Round-3 work decomposition (176 blocks: 8j x 11m x 2d), cooperative launch
// for co-residency ONLY.  Per step: h exchanged via sc0/sc1 (Infinity Cache,
// device-coherent; per-XCD L2s bypassed), flat atomic barrier at LLC.
// c-state lives in registers (same thread owns same cells every step).
// h double-buffer prevents WAR across one barrier.  x_out written PACKED.
// ---------------------------------------------------------------------------
__global__ __launch_bounds__(256)
void lstm_scan_k(const float* __restrict__ G,              // [32*341][2048]
                 const unsigned short* __restrict__ Whi,   // [2][1024][256]
                 const unsigned short* __restrict__ Wlo,
                 float* __restrict__ hb,                   // [2][2*341*256] dbuf
                 unsigned short* __restrict__ x_out,       // [32*341] packed rows of 512
                 unsigned* __restrict__ bar)               // zeroed before launch
{
    const int j0 = blockIdx.x * 32;
    const int m0 = blockIdx.y * 32;
    const int d  = blockIdx.z;
    const int tid = threadIdx.x;
    const int w = tid >> 6, lane = tid & 63;
    const int mhalf = w & 1, gpair = w >> 1;
    const int ln15 = lane & 15, lq = lane >> 4;
    const size_t hsz = (size_t)2*SP*HD;

    __shared__ float Csh[32][132];

    int am = m0 + mhalf*16 + ln15; if (am > SP-1) am = SP-1;   // A row (clamped)
    const int akoff = lq * 8;

    const unsigned short* WhiD = Whi + (size_t)d*1024*256;
    const unsigned short* WloD = Wlo + (size_t)d*1024*256;
    int nrow[4];
    #pragma unroll
    for (int t = 0; t < 4; ++t)
        nrow[t] = (gpair*2 + (t>>1))*256 + j0 + (t&1)*16 + ln15;

    const int emloc = tid >> 3;           // 0..31 local row
    const int ej4   = (tid & 7) * 4;      // 0..28 local col (x4)
    const int em    = m0 + emloc;

    floatx4 creg = (floatx4){0.f, 0.f, 0.f, 0.f};   // c-state in registers

    for (int s = 0; s < B_; ++s) {
        const int t_in = d ? (B_ - 1 - s) : s;
        float* hbuf_in  = hb + (size_t)(s & 1)*hsz;
        float* hbuf_out = hb + (size_t)((s+1) & 1)*hsz;

        floatx4 acc[4];
        #pragma unroll
        for (int t = 0; t < 4; ++t) acc[t] = (floatx4){0.f, 0.f, 0.f, 0.f};

        if (s > 0) {
            const float* p = hbuf_in + (size_t)d*HS + (size_t)am*HD + akoff;
            floatx4 hr[16];
            load_h16_llc(p, hr);
            #pragma unroll
            for (int kk = 0; kk < 8; ++kk) {
                const int ko = kk*32 + akoff;
                float vv[8] = {hr[2*kk][0], hr[2*kk][1], hr[2*kk][2], hr[2*kk][3],
                               hr[2*kk+1][0], hr[2*kk+1][1], hr[2*kk+1][2], hr[2*kk+1][3]};
                short8 ahi, alo;
                #pragma unroll
                for (int e = 0; e < 8; ++e) {
                    unsigned short hb16 = f2bf(vv[e]);
                    ahi[e] = (short)hb16;
                    alo[e] = (short)f2bf(vv[e] - bf2f(hb16));
                }
                #pragma unroll
                for (int t = 0; t < 4; ++t) {
                    short8 bhi = *(const short8*)(WhiD + (size_t)nrow[t]*HD + ko);
                    short8 blo = *(const short8*)(WloD + (size_t)nrow[t]*HD + ko);
                    acc[t] = __builtin_amdgcn_mfma_f32_16x16x32_bf16(alo, bhi, acc[t], 0, 0, 0);
                    acc[t] = __builtin_amdgcn_mfma_f32_16x16x32_bf16(ahi, blo, acc[t], 0, 0, 0);
                    acc[t] = __builtin_amdgcn_mfma_f32_16x16x32_bf16(ahi, bhi, acc[t], 0, 0, 0);
                }
            }
        }

        // dump C fragments to LDS (D: col=lane&15, row=lq*4+reg)
        #pragma unroll
        for (int t = 0; t < 4; ++t) {
            int col = gpair*64 + (t>>1)*32 + (t&1)*16 + ln15;
            int rb  = mhalf*16 + lq*4;
            #pragma unroll
            for (int r = 0; r < 4; ++r)
                Csh[rb + r][col] = acc[t][r];
        }
        __syncthreads();

        if (em < SP) {
            size_t gb = ((size_t)t_in*SP + em)*2048 + (size_t)d*1024 + j0 + ej4;
            float4 gi4 = *(const float4*)&G[gb];
            float4 gf4 = *(const float4*)&G[gb + 256];
            float4 gg4 = *(const float4*)&G[gb + 512];
            float4 go4 = *(const float4*)&G[gb + 768];
            float hv[4];
            #pragma unroll
            for (int e = 0; e < 4; ++e) {
                float gi = Csh[emloc][     ej4+e] + (&gi4.x)[e];
                float gf = Csh[emloc][32 + ej4+e] + (&gf4.x)[e];
                float gg = Csh[emloc][64 + ej4+e] + (&gg4.x)[e];
                float go = Csh[emloc][96 + ej4+e] + (&go4.x)[e];
                float cn = sigmoidf_(gf)*creg[e] + sigmoidf_(gi)*tanhf(gg);
                creg[e] = cn;
                hv[e] = sigmoidf_(go)*tanhf(cn);
            }
            size_t cbase = ((size_t)d*SP + em)*HD + j0 + ej4;
            floatx4 ho = (floatx4){hv[0], hv[1], hv[2], hv[3]};
            store_f4_llc(&hbuf_out[cbase], ho);          // LLC-coherent h store
            // packed x_out write (normal cached; consumed after kernel end)
            const int colg = d*HD + j0 + ej4;
            size_t xb = ((size_t)t_in*SP + em)*1024 + (size_t)(colg >> 3)*16 + (colg & 7);
            ushortx4 xh, xl;
            #pragma unroll
            for (int e = 0; e < 4; ++e) {
                unsigned short hb16 = f2bf(hv[e]);
                xh[e] = hb16;
                xl[e] = f2bf(hv[e] - bf2f(hb16));
            }
            *(ushortx4*)&x_out[xb]     = xh;
            *(ushortx4*)&x_out[xb + 8] = xl;
        }

        if (s < B_ - 1) {
            // all waves drain their own h stores to LLC, then block-arrive
            asm volatile("s_waitcnt vmcnt(0)" ::: "memory");
            __syncthreads();
            if (tid == 0) {
                atomicAdd(bar, 1u);                          // device-scope (LLC)
                const unsigned target = (unsigned)(s + 1) * NBLK;
                while (load_u32_llc(bar) < target)
                    __builtin_amdgcn_s_sleep(2);
            }
            __syncthreads();
        }
    }
}

// ---------------------------------------------------------------------------
// Kernel 4a: scores tile (64x64), RPE analytic.
// ---------------------------------------------------------------------------
__global__ __launch_bounds__(256)
void scores_k(const float* __restrict__ q, const float* __restrict__ k,
              float* __restrict__ P, int g)
{
    const int h = blockIdx.z, bl = blockIdx.y, bg = g*GRP + bl;
    const int q0 = (blockIdx.x / 6) * 64;
    const int k0 = (blockIdx.x % 6) * 64;
    const int tid = threadIdx.x;
    __shared__ float qs[64][68];
    __shared__ float ks[64][68];
    {
        int jr = tid >> 2, c16 = (tid & 3) * 16;
        int qq = q0 + jr; if (qq > SP-1) qq = SP-1;
        int kr = k0 + jr; if (kr > SP-1) kr = SP-1;
        const float* qp = &q[((size_t)bg*SP + qq)*512 + h*64 + c16];
        const float* kp = &k[((size_t)bg*SP + kr)*512 + h*64 + c16];
        #pragma unroll
        for (int u = 0; u < 4; ++u) {
            *(float4*)&qs[jr][c16 + u*4] = *(const float4*)(qp + u*4);
            *(float4*)&ks[jr][c16 + u*4] = *(const float4*)(kp + u*4);
        }
    }
    __syncthreads();
    const int tx = tid & 15, ty = tid >> 4;
    float acc[4][4];
    #pragma unroll
    for (int i = 0; i < 4; ++i)
        #pragma unroll
        for (int j = 0; j < 4; ++j) acc[i][j] = 0.0f;
    for (int d4 = 0; d4 < 64; d4 += 4) {
        float4 a[4], b[4];
        #pragma unroll
        for (int i = 0; i < 4; ++i) a[i] = *(const float4*)&qs[ty + 16*i][d4];
        #pragma unroll
        for (int j = 0; j < 4; ++j) b[j] = *(const float4*)&ks[tx + 16*j][d4];
        #pragma unroll
        for (int i = 0; i < 4; ++i)
            #pragma unroll
            for (int j = 0; j < 4; ++j)
                acc[i][j] += a[i].x*b[j].x + a[i].y*b[j].y + a[i].z*b[j].z + a[i].w*b[j].w;
    }
    #pragma unroll
    for (int i = 0; i < 4; ++i) {
        int qq = q0 + ty + 16*i;
        if (qq >= SP) continue;
        int r0 = 6*qq - 1; if (r0 < 0) r0 = 0;
        int r1 = 6*qq + 7; if (r1 > SLEN-1) r1 = SLEN-1;
        size_t rowb = ((size_t)(h*GRP + bl)*SP + qq) * PSTR;
        #pragma unroll
        for (int j = 0; j < 4; ++j) {
            int kk = k0 + tx + 16*j;
            if (kk >= SP) continue;
            int c0 = 6*kk - 1; if (c0 < 0) c0 = 0;
            int c1 = 6*kk + 7;
            int dd1 = c1 - r0; if (dd1 < 0) dd1 = -dd1;
            int dd2 = r1 - c0; if (dd2 < 0) dd2 = -dd2;
            int den = dd1 > dd2 ? dd1 : dd2;
            P[rowb + kk] = (acc[i][j] * 0.125f) * 2047.0f / (float)den;
        }
    }
}

// ---------------------------------------------------------------------------
// Kernel 4b: row softmax in place.
// ---------------------------------------------------------------------------
__global__ __launch_bounds__(256)
void softmax_k(float* __restrict__ P)
{
    const int tid = threadIdx.x;
    const int row = blockIdx.x * 4 + (tid >> 6);
    const int lane = tid & 63;
    float* rp = P + (size_t)row * PSTR;
    float v[6];
    float m = -1e30f;
    #pragma unroll
    for (int i = 0; i < 6; ++i) {
        int col = lane + 64*i;
        v[i] = (col < SP) ? rp[col] : -1e30f;
        m = fmaxf(m, v[i]);
    }
    #pragma unroll
    for (int o = 1; o < 64; o <<= 1) m = fmaxf(m, __shfl_xor(m, o, 64));
    float s = 0.0f;
    #pragma unroll
    for (int i = 0; i < 6; ++i) {
        v[i] = expf(v[i] - m);
        s += v[i];
    }
    #pragma unroll
    for (int o = 1; o < 64; o <<= 1) s += __shfl_xor(s, o, 64);
    float inv = 1.0f / s;
    #pragma unroll
    for (int i = 0; i < 6; ++i) {
        int col = lane + 64*i;
        if (col < SP) rp[col] = v[i] * inv;
    }
}

// ---------------------------------------------------------------------------
// Kernel 4c: out = relu(P @ V), K=SP in 6x64 chunks. cat written PACKED.
// ---------------------------------------------------------------------------
__global__ __launch_bounds__(256)
void pv_k(const float* __restrict__ P, const float* __restrict__ v,
          unsigned short* __restrict__ catp, int g)
{
    const int h = blockIdx.z, bl = blockIdx.y, bg = g*GRP + bl;
    const int q0 = blockIdx.x * 64;
    const int tid = threadIdx.x;
    __shared__ float ps[64][68];
    __shared__ float vs[64][68];
    const int tx = tid & 15, ty = tid >> 4;
    float acc[4][4];
    #pragma unroll
    for (int i = 0; i < 4; ++i)
        #pragma unroll
        for (int j = 0; j < 4; ++j) acc[i][j] = 0.0f;

    for (int kc = 0; kc < 6; ++kc) {
        const int kk0 = kc * 64;
        {
            int jr = tid >> 2, c16 = (tid & 3) * 16;
            int qq = q0 + jr; if (qq > SP-1) qq = SP-1;
            const float* pp = P + ((size_t)(h*GRP + bl)*SP + qq)*PSTR + kk0 + c16;
            #pragma unroll
            for (int u = 0; u < 4; ++u) {
                float4 w = *(const float4*)(pp + u*4);
                int klb = c16 + u*4;
                float vals[4] = {w.x, w.y, w.z, w.w};
                #pragma unroll
                for (int e = 0; e < 4; ++e)
                    ps[klb + e][jr] = (kk0 + klb + e < SP) ? vals[e] : 0.0f;
            }
        }
        {
            int jr = tid >> 2, c16 = (tid & 3) * 16;
            int kr = kk0 + jr; if (kr > SP-1) kr = SP-1;
            const float* vp = &v[((size_t)bg*SP + kr)*512 + h*64 + c16];
            #pragma unroll
            for (int u = 0; u < 4; ++u)
                *(float4*)&vs[jr][c16 + u*4] = *(const float4*)(vp + u*4);
        }
        __syncthreads();
        for (int kk = 0; kk < 64; ++kk) {
            float4 a4 = *(const float4*)&ps[kk][ty*4];
            float4 b4 = *(const float4*)&vs[kk][tx*4];
            float av[4] = {a4.x, a4.y, a4.z, a4.w};
            float bv[4] = {b4.x, b4.y, b4.z, b4.w};
            #pragma unroll
            for (int i = 0; i < 4; ++i)
                #pragma unroll
                for (int j = 0; j < 4; ++j)
                    acc[i][j] += av[i] * bv[j];
        }
        __syncthreads();
    }
    #pragma unroll
    for (int i = 0; i < 4; ++i) {
        int qq = q0 + ty*4 + i;
        if (qq >= SP) continue;
        float r[4];
        r[0] = fmaxf(acc[i][0], 0.0f);
        r[1] = fmaxf(acc[i][1], 0.0f);
        r[2] = fmaxf(acc[i][2], 0.0f);
        r[3] = fmaxf(acc[i][3], 0.0f);
        const int colg = h*64 + tx*4;
        size_t xb = ((size_t)bg*SP + qq)*1024 + (size_t)(colg >> 3)*16 + (colg & 7);
        ushortx4 xh, xl;
        #pragma unroll
        for (int e = 0; e < 4; ++e) {
            unsigned short hb16 = f2bf(r[e]);
            xh[e] = hb16;
            xl[e] = f2bf(r[e] - bf2f(hb16));
        }
        *(ushortx4*)&catp[xb]     = xh;
        *(ushortx4*)&catp[xb + 8] = xl;
    }
}

// ---------------------------------------------------------------------------
extern "C" void kernel_launch(void* const* d_in, const int* in_sizes, int n_in,
                              void* d_out, int out_size, void* d_ws, size_t ws_size,
                              hipStream_t stream)
{
    (void)in_sizes; (void)n_in; (void)out_size; (void)ws_size;
    const float* in    = (const float*)d_in[0];
    const float* cw    = (const float*)d_in[1];
    const float* gamma = (const float*)d_in[2];
    const float* beta  = (const float*)d_in[3];
    const float* Wih0  = (const float*)d_in[4];
    const float* Whh0  = (const float*)d_in[5];
    const float* b0    = (const float*)d_in[6];
    const float* Wih1  = (const float*)d_in[7];
    const float* Whh1  = (const float*)d_in[8];
    const float* b1    = (const float*)d_in[9];
    const float* Qw    = (const float*)d_in[10];
    const float* Qb    = (const float*)d_in[11];
    const float* Kw    = (const float*)d_in[12];
    const float* Kb    = (const float*)d_in[13];
    const float* Vw    = (const float*)d_in[14];
    const float* Vb    = (const float*)d_in[15];
    const float* mhw   = (const float*)d_in[16];
    const float* mhb   = (const float*)d_in[17];
    float* out = (float*)d_out;

    // workspace arena (floats). Same region map as before.
    float* x0 = (float*)d_ws;                                   //  2,793,472 f
    float* G  = x0 + (size_t)RTOT*NF;                           // 22,347,776 f
    float* x1 = G  + (size_t)RTOT*2048;                         //  5,586,944 f
    float* x2 = x1 + (size_t)RTOT*512;                          //  5,586,944 f
    float* hb = x2 + (size_t)RTOT*512;                          //    349,184 f
    float* cb = hb + (size_t)2*2*SP*HD;                         //    174,592 f (c now in regs; holds barrier)

    float* qbuf = G;
    float* kbuf = G + (size_t)RTOT*512;
    float* vbuf = G + (size_t)2*RTOT*512;
    float* P    = G + (size_t)3*RTOT*512;
    unsigned* bar = (unsigned*)cb;

    // ---- packed-buffer aliases (each placed in a region dead at time of use) ----
    unsigned short* x0p = (unsigned short*)x0;
    unsigned short* whh1_hi = (unsigned short*)x0;                         // after gemm1
    unsigned short* whh1_lo = whh1_hi + (size_t)524288;
    unsigned short* wih0_p  = (unsigned short*)x2;
    unsigned short* wih1_p  = wih0_p + (size_t)1048576;
    unsigned short* whh0_hi = wih1_p + (size_t)2097152;
    unsigned short* whh0_lo = whh0_hi + (size_t)524288;
    unsigned short* x1p  = (unsigned short*)x1;
    unsigned short* catp = (unsigned short*)x1;
    unsigned short* x2p = (unsigned short*)x2;
    float* gslack = P + (size_t)NH_*GRP*SP*PSTR;
    unsigned short* qw_p = (unsigned short*)gslack;
    unsigned short* kw_p = qw_p + (size_t)524288;
    unsigned short* vw_p = kw_p + (size_t)524288;
    unsigned short* mw_p = vw_p + (size_t)524288;

    #define PACKGRID(n) dim3(((n) + 255) / 256)

    // 1. conv+bn+relu+pool -> x0p (packed)
    conv_pool_k<<<dim3(22, B_), 256, 0, stream>>>(in, cw, gamma, beta, x0p);
    // 2. pack Wih0 (octet) into x2 region
    pack8_k<<<PACKGRID(65536), 256, 0, stream>>>(Wih0, wih0_p, 65536);
    // 3. layer-1 input gates: G = x0 @ Wih0^T + b0   (K=256)
    gemm_bf_k<0><<<dim3(16, 86), 256, 0, stream>>>(x0p, wih0_p, b0, G, RTOT, 2048, 256);
    // 4. pack Whh0 (x2 tail), Whh1 (x0 region, dead after gemm1), Wih1 (x2)
    pack4_k<<<PACKGRID(131072), 256, 0, stream>>>(Whh0, whh0_hi, whh0_lo, 131072);
    pack4_k<<<PACKGRID(131072), 256, 0, stream>>>(Whh1, whh1_hi, whh1_lo, 131072);
    pack8_k<<<PACKGRID(131072), 256, 0, stream>>>(Wih1, wih1_p, 131072);
    // 5. layer-1 scan -> x1p (persistent, custom LLC barrier)
    hipMemsetAsync(bar, 0, sizeof(unsigned), stream);
    {
        const float* a0 = G; const unsigned short* a1 = whh0_hi; const unsigned short* a2 = whh0_lo;
        float* a3 = hb; unsigned short* a4 = x1p; unsigned* a5 = bar;
        void* kargs[] = {&a0, &a1, &a2, &a3, &a4, &a5};
        hipLaunchCooperativeKernel((void*)lstm_scan_k, dim3(8, 11, 2), dim3(256, 1, 1), kargs, 0, stream);
    }
    // 6. layer-2 input gates: G = x1 @ Wih1^T + b1   (K=512)
    gemm_bf_k<0><<<dim3(16, 86), 256, 0, stream>>>(x1p, wih1_p, b1, G, RTOT, 2048, 512);
    // 7. layer-2 scan -> x2p
    hipMemsetAsync(bar, 0, sizeof(unsigned), stream);
    {
        const float* a0 = G; const unsigned short* a1 = whh1_hi; const unsigned short* a2 = whh1_lo;
        float* a3 = hb; unsigned short* a4 = x2p; unsigned* a5 = bar;
        void* kargs[] = {&a0, &a1, &a2, &a3, &a4, &a5};
        hipLaunchCooperativeKernel((void*)lstm_scan_k, dim3(8, 11, 2), dim3(256, 1, 1), kargs, 0, stream);
    }
    // 8. pack QKV/mh weights into G tail slack (G-as-gates dead)
    pack8_k<<<PACKGRID(32768), 256, 0, stream>>>(Qw,  qw_p, 32768);
    pack8_k<<<PACKGRID(32768), 256, 0, stream>>>(Kw,  kw_p, 32768);
    pack8_k<<<PACKGRID(32768), 256, 0, stream>>>(Vw,  vw_p, 32768);
    pack8_k<<<PACKGRID(32768), 256, 0, stream>>>(mhw, mw_p, 32768);
    // 9. Q/K/V projections (fp32 outputs into G region)
    gemm_bf_k<0><<<dim3(4, 86), 256, 0, stream>>>(x2p, qw_p, Qb, qbuf, RTOT, 512, 512);
    gemm_bf_k<0><<<dim3(4, 86), 256, 0, stream>>>(x2p, kw_p, Kb, kbuf, RTOT, 512, 512);
    gemm_bf_k<0><<<dim3(4, 86), 256, 0, stream>>>(x2p, vw_p, Vb, vbuf, RTOT, 512, 512);
    // 10. attention in GRP-batch groups; pv writes catp (x1 region, packed)
    for (int g = 0; g < B_/GRP; ++g) {
        scores_k <<<dim3(36, GRP, NH_), 256, 0, stream>>>(qbuf, kbuf, P, g);
        softmax_k<<<dim3(NH_*GRP*SP/4), 256, 0, stream>>>(P);
        pv_k     <<<dim3(6, GRP, NH_), 256, 0, stream>>>(P, vbuf, catp, g);
    }
    // 11. final linear + relu
    gemm_bf_k<1><<<dim3(4, 86), 256, 0, stream>>>(catp, mw_p, mhb, out, RTOT, 512, 512);
    #undef PACKGRID
}

// Round 6
// 1643.225 us; speedup vs baseline: 1.8250x; 1.1612x over previous
//
#include <hip/hip_runtime.h>
#include <math.h>

// Problem constants
#define B_    32
#define CIN   4
#define SLEN  2048
#define NF    256
#define HD    256          // LSTM hidden per direction
#define SP    341          // post conv+pool sequence length
#define RTOT  (B_*SP)      // 10912 rows
#define NH_   8
#define DH_   64
#define GRP   4            // batches per attention group
#define PSTR  344          // padded P row stride (16B-aligned)
#define HS    (SP*HD)      // 87296: per-dir h elems
#define NBLK  176          // scan grid: 8 x 11 x 2

typedef __attribute__((ext_vector_type(8))) short short8;
typedef __attribute__((ext_vector_type(4))) float floatx4;
typedef __attribute__((ext_vector_type(4))) unsigned short ushortx4;
typedef __attribute__((ext_vector_type(8))) unsigned short ushort8;

__device__ __forceinline__ float sigmoidf_(float x) { return 1.0f / (1.0f + expf(-x)); }

__device__ __forceinline__ unsigned short f2bf(float x) {
    unsigned int u = __float_as_uint(x);
    unsigned int r = (u + 0x7FFF + ((u >> 16) & 1)) >> 16;   // RNE
    return (unsigned short)r;
}
__device__ __forceinline__ float bf2f(unsigned short b) {
    return __uint_as_float(((unsigned int)b) << 16);
}

// ---- LLC-coherent (Infinity Cache) access helpers: sc0 sc1 bypass L1/L2 ----
__device__ __forceinline__ void store_f4_llc(float* p, floatx4 v)
{
    asm volatile("global_store_dwordx4 %0, %1, off sc0 sc1" :: "v"(p), "v"(v) : "memory");
}
__device__ __forceinline__ unsigned load_u32_llc(const unsigned* p)
{
    unsigned r;
    asm volatile("global_load_dword %0, %1, off sc0 sc1\n\ts_waitcnt vmcnt(0)"
                 : "=v"(r) : "v"(p) : "memory");
    return r;
}
// 16 x dwordx4 from one base (offsets kk*128 and kk*128+16), single trailing
// waitcnt INSIDE the asm so no use can be scheduled before data lands.
__device__ __forceinline__ void load_h16_llc(const float* p, floatx4* r)
{
    asm volatile(
        "global_load_dwordx4 %0, %16, off sc0 sc1\n\t"
        "global_load_dwordx4 %1, %16, off offset:16 sc0 sc1\n\t"
        "global_load_dwordx4 %2, %16, off offset:128 sc0 sc1\n\t"
        "global_load_dwordx4 %3, %16, off offset:144 sc0 sc1\n\t"
        "global_load_dwordx4 %4, %16, off offset:256 sc0 sc1\n\t"
        "global_load_dwordx4 %5, %16, off offset:272 sc0 sc1\n\t"
        "global_load_dwordx4 %6, %16, off offset:384 sc0 sc1\n\t"
        "global_load_dwordx4 %7, %16, off offset:400 sc0 sc1\n\t"
        "global_load_dwordx4 %8, %16, off offset:512 sc0 sc1\n\t"
        "global_load_dwordx4 %9, %16, off offset:528 sc0 sc1\n\t"
        "global_load_dwordx4 %10, %16, off offset:640 sc0 sc1\n\t"
        "global_load_dwordx4 %11, %16, off offset:656 sc0 sc1\n\t"
        "global_load_dwordx4 %12, %16, off offset:768 sc0 sc1\n\t"
        "global_load_dwordx4 %13, %16, off offset:784 sc0 sc1\n\t"
        "global_load_dwordx4 %14, %16, off offset:896 sc0 sc1\n\t"
        "global_load_dwordx4 %15, %16, off offset:912 sc0 sc1\n\t"
        "s_waitcnt vmcnt(0)"
        : "=&v"(r[0]), "=&v"(r[1]), "=&v"(r[2]), "=&v"(r[3]),
          "=&v"(r[4]), "=&v"(r[5]), "=&v"(r[6]), "=&v"(r[7]),
          "=&v"(r[8]), "=&v"(r[9]), "=&v"(r[10]), "=&v"(r[11]),
          "=&v"(r[12]), "=&v"(r[13]), "=&v"(r[14]), "=&v"(r[15])
        : "v"(p)
        : "memory");
}

// ---------------------------------------------------------------------------
// Packed bf16 hi/lo "octet" layout: for a row of K fp32 values, the packed row
// has 2K ushorts: octet o (elems 8o..8o+7) occupies ushorts [16o..16o+7]=hi,
// [16o+8..16o+15]=lo.  One K-step of 32 elems = 128 contiguous bytes.
// ---------------------------------------------------------------------------

// Kernel 1: Conv1d(4->256,k13,pad6)+BN+ReLU+MaxPool1d(6) -> x0 packed
__global__ __launch_bounds__(256)
void conv_pool_k(const float* __restrict__ in, const float* __restrict__ cw,
                 const float* __restrict__ gamma, const float* __restrict__ beta,
                 unsigned short* __restrict__ x0p)
{
    const int b  = blockIdx.y;
    const int s0 = blockIdx.x * 16;
    const int co = threadIdx.x;
    __shared__ float ins[CIN][16*6 + 12];
    for (int idx = threadIdx.x; idx < CIN*108; idx += 256) {
        int ci = idx / 108, o = idx % 108;
        int pos = 6*s0 - 6 + o;
        ins[ci][o] = (pos >= 0 && pos < SLEN) ? in[(b*CIN + ci)*SLEN + pos] : 0.0f;
    }
    float wreg[52];
    {
        const float4* wp = (const float4*)(cw + co*52);
        #pragma unroll
        for (int j4 = 0; j4 < 13; ++j4) {
            float4 w4 = wp[j4];
            wreg[j4*4+0]=w4.x; wreg[j4*4+1]=w4.y; wreg[j4*4+2]=w4.z; wreg[j4*4+3]=w4.w;
        }
    }
    const float scale = gamma[co] * (1.0f / sqrtf(1.0f + 1e-5f));
    const float shift = beta[co];
    __syncthreads();
    for (int si = 0; si < 16; ++si) {
        int s = s0 + si;
        if (s >= SP) break;
        float win[CIN][18];
        #pragma unroll
        for (int ci = 0; ci < CIN; ++ci)
            #pragma unroll
            for (int o = 0; o < 18; ++o)
                win[ci][o] = ins[ci][6*si + o];
        float m = -1e30f;
        #pragma unroll
        for (int p6 = 0; p6 < 6; ++p6) {
            float acc = 0.0f;
            #pragma unroll
            for (int ci = 0; ci < CIN; ++ci)
                #pragma unroll
                for (int kk = 0; kk < 13; ++kk)
                    acc += win[ci][p6+kk] * wreg[ci*13+kk];
            float val = acc * scale + shift;
            val = fmaxf(val, 0.0f);
            m = fmaxf(m, val);
        }
        unsigned short hb_ = f2bf(m);
        unsigned short lb_ = f2bf(m - bf2f(hb_));
        size_t rb = (size_t)(b*SP + s)*512 + (size_t)(co >> 3)*16 + (co & 7);
        x0p[rb]     = hb_;
        x0p[rb + 8] = lb_;
    }
}

// Kernel 2a: fp32 -> separate hi/lo pack (for lstm Whh, layout unchanged)
__global__ __launch_bounds__(256)
void pack4_k(const float* __restrict__ W, unsigned short* __restrict__ hi,
             unsigned short* __restrict__ lo, int n4)
{
    int i = blockIdx.x * 256 + threadIdx.x;
    if (i >= n4) return;
    float4 x = *((const float4*)W + i);
    float v[4] = {x.x, x.y, x.z, x.w};
    ushortx4 h, l;
    #pragma unroll
    for (int e = 0; e < 4; ++e) {
        unsigned short hb = f2bf(v[e]);
        h[e] = hb;
        l[e] = f2bf(v[e] - bf2f(hb));
    }
    *((ushortx4*)hi + i) = h;
    *((ushortx4*)lo + i) = l;
}

// Kernel 2b: fp32 -> interleaved octet pack (8 elems/thread)
__global__ __launch_bounds__(256)
void pack8_k(const float* __restrict__ W, unsigned short* __restrict__ O, int n8)
{
    int i = blockIdx.x * 256 + threadIdx.x;
    if (i >= n8) return;
    const float4* wp = (const float4*)W + (size_t)i*2;
    float4 a = wp[0], b = wp[1];
    float v[8] = {a.x,a.y,a.z,a.w,b.x,b.y,b.z,b.w};
    ushort8 h, l;
    #pragma unroll
    for (int e = 0; e < 8; ++e) {
        unsigned short hb = f2bf(v[e]);
        h[e] = hb;
        l[e] = f2bf(v[e] - bf2f(hb));
    }
    *(ushort8*)(O + (size_t)i*16)     = h;
    *(ushort8*)(O + (size_t)i*16 + 8) = l;
}

// ---------------------------------------------------------------------------
// Kernel 3: split-bf16 MFMA GEMM, operands in packed octet layout.
// (unchanged from round 3)
// ---------------------------------------------------------------------------
template<int RELU>
__global__ __launch_bounds__(256)
void gemm_bf_k(const unsigned short* __restrict__ Ap, const unsigned short* __restrict__ Bp,
               const float* __restrict__ bias, float* __restrict__ C,
               int M, int N, int K)
{
    const int n0 = blockIdx.x * 128;
    const int m0 = blockIdx.y * 128;
    const int tid = threadIdx.x;
    const int lane = tid & 63;
    const int w = tid >> 6;
    const int wm = w >> 1, wn = w & 1;
    const int ln15 = lane & 15, lq = lane >> 4;
    const int l8 = lane >> 3, lj = lane & 7;
    const size_t rstr = 2*(size_t)K;

    __shared__ unsigned short As[128*64];
    __shared__ unsigned short Bs[128*64];

    floatx4 acc[4][4];
    #pragma unroll
    for (int i = 0; i < 4; ++i)
        #pragma unroll
        for (int j = 0; j < 4; ++j) acc[i][j] = (floatx4){0.f, 0.f, 0.f, 0.f};

    int rloc[4];
    #pragma unroll
    for (int c = 0; c < 4; ++c) rloc[c] = w*32 + c*8 + l8;
    const int spos = lj ^ (l8 & 7);

    for (int k0 = 0; k0 < K; k0 += 32) {
        short8 va[4], vb[4];
        #pragma unroll
        for (int c = 0; c < 4; ++c) {
            int gra = m0 + rloc[c]; if (gra >= M) gra = M - 1;
            va[c] = *(const short8*)(Ap + (size_t)gra*rstr + k0*2 + lj*8);
            vb[c] = *(const short8*)(Bp + (size_t)(n0 + rloc[c])*rstr + k0*2 + lj*8);
        }
        __syncthreads();
        #pragma unroll
        for (int c = 0; c < 4; ++c) {
            *(short8*)&As[rloc[c]*64 + spos*8] = va[c];
            *(short8*)&Bs[rloc[c]*64 + spos*8] = vb[c];
        }
        __syncthreads();

        short8 fa_h[4], fa_l[4], fb_h[4], fb_l[4];
        #pragma unroll
        for (int mt = 0; mt < 4; ++mt) {
            const int lr = wm*64 + mt*16 + ln15;
            fa_h[mt] = *(const short8*)&As[lr*64 + (((lq*2  ) ^ (lr&7))*8)];
            fa_l[mt] = *(const short8*)&As[lr*64 + (((lq*2+1) ^ (lr&7))*8)];
        }
        #pragma unroll
        for (int nt = 0; nt < 4; ++nt) {
            const int lr = wn*64 + nt*16 + ln15;
            fb_h[nt] = *(const short8*)&Bs[lr*64 + (((lq*2  ) ^ (lr&7))*8)];
            fb_l[nt] = *(const short8*)&Bs[lr*64 + (((lq*2+1) ^ (lr&7))*8)];
        }
        #pragma unroll
        for (int mt = 0; mt < 4; ++mt)
            #pragma unroll
            for (int nt = 0; nt < 4; ++nt) {
                acc[mt][nt] = __builtin_amdgcn_mfma_f32_16x16x32_bf16(fa_l[mt], fb_h[nt], acc[mt][nt], 0, 0, 0);
                acc[mt][nt] = __builtin_amdgcn_mfma_f32_16x16x32_bf16(fa_h[mt], fb_l[nt], acc[mt][nt], 0, 0, 0);
                acc[mt][nt] = __builtin_amdgcn_mfma_f32_16x16x32_bf16(fa_h[mt], fb_h[nt], acc[mt][nt], 0, 0, 0);
            }
    }

    #pragma unroll
    for (int nt = 0; nt < 4; ++nt) {
        const int n = n0 + wn*64 + nt*16 + ln15;
        const float bv = bias[n];
        #pragma unroll
        for (int mt = 0; mt < 4; ++mt) {
            const int mbase = m0 + wm*64 + mt*16 + lq*4;
            #pragma unroll
            for (int r = 0; r < 4; ++r) {
                int m = mbase + r;
                if (m < M) {
                    float val = acc[mt][nt][r] + bv;
                    if (RELU) val = fmaxf(val, 0.0f);
                    C[(size_t)m*N + n] = val;
                }
            }
        }
    }
}

// ---------------------------------------------------------------------------
// Kernel 3b: PERSISTENT LSTM scan, GROUP-LOCAL LLC barrier.
// Dataflow: block (j0,m0,d) reads h rows [m0,m0+32) (all K cols), written by
// exactly the 8 blocks sharing (m0,d).  So sync is per-(m0,d) group of 8 —
// 22 independent groups, each with its own counter (256B-strided cachelines).
// 8 atomics/counter/step instead of 176 on one line (round-5 bottleneck).
// c-state in registers; h via sc0/sc1 (LLC-coherent); h dbuf handles WAR.
// ---------------------------------------------------------------------------
__global__ __launch_bounds__(256)
void lstm_scan_k(const float* __restrict__ G,              // [32*341][2048]
                 const unsigned short* __restrict__ Whi,   // [2][1024][256]
                 const unsigned short* __restrict__ Wlo,
                 float* __restrict__ hb,                   // [2][2*341*256] dbuf
                 unsigned short* __restrict__ x_out,       // [32*341] packed rows of 512
                 unsigned* __restrict__ bar)               // [22*64], zeroed
{
    const int j0 = blockIdx.x * 32;
    const int m0 = blockIdx.y * 32;
    const int d  = blockIdx.z;
    const int tid = threadIdx.x;
    const int w = tid >> 6, lane = tid & 63;
    const int mhalf = w & 1, gpair = w >> 1;
    const int ln15 = lane & 15, lq = lane >> 4;
    const size_t hsz = (size_t)2*SP*HD;
    unsigned* gbar = bar + (size_t)(blockIdx.y*2 + blockIdx.z)*64;  // group counter

    __shared__ float Csh[32][132];

    int am = m0 + mhalf*16 + ln15; if (am > SP-1) am = SP-1;   // A row (clamped, stays in own m-tile)
    const int akoff = lq * 8;

    const unsigned short* WhiD = Whi + (size_t)d*1024*256;
    const unsigned short* WloD = Wlo + (size_t)d*1024*256;
    int nrow[4];
    #pragma unroll
    for (int t = 0; t < 4; ++t)
        nrow[t] = (gpair*2 + (t>>1))*256 + j0 + (t&1)*16 + ln15;

    const int emloc = tid >> 3;           // 0..31 local row
    const int ej4   = (tid & 7) * 4;      // 0..28 local col (x4)
    const int em    = m0 + emloc;

    floatx4 creg = (floatx4){0.f, 0.f, 0.f, 0.f};   // c-state in registers

    for (int s = 0; s < B_; ++s) {
        const int t_in = d ? (B_ - 1 - s) : s;
        float* hbuf_in  = hb + (size_t)(s & 1)*hsz;
        float* hbuf_out = hb + (size_t)((s+1) & 1)*hsz;

        floatx4 acc[4];
        #pragma unroll
        for (int t = 0; t < 4; ++t) acc[t] = (floatx4){0.f, 0.f, 0.f, 0.f};

        if (s > 0) {
            const float* p = hbuf_in + (size_t)d*HS + (size_t)am*HD + akoff;
            floatx4 hr[16];
            load_h16_llc(p, hr);
            #pragma unroll
            for (int kk = 0; kk < 8; ++kk) {
                const int ko = kk*32 + akoff;
                float vv[8] = {hr[2*kk][0], hr[2*kk][1], hr[2*kk][2], hr[2*kk][3],
                               hr[2*kk+1][0], hr[2*kk+1][1], hr[2*kk+1][2], hr[2*kk+1][3]};
                short8 ahi, alo;
                #pragma unroll
                for (int e = 0; e < 8; ++e) {
                    unsigned short hb16 = f2bf(vv[e]);
                    ahi[e] = (short)hb16;
                    alo[e] = (short)f2bf(vv[e] - bf2f(hb16));
                }
                #pragma unroll
                for (int t = 0; t < 4; ++t) {
                    short8 bhi = *(const short8*)(WhiD + (size_t)nrow[t]*HD + ko);
                    short8 blo = *(const short8*)(WloD + (size_t)nrow[t]*HD + ko);
                    acc[t] = __builtin_amdgcn_mfma_f32_16x16x32_bf16(alo, bhi, acc[t], 0, 0, 0);
                    acc[t] = __builtin_amdgcn_mfma_f32_16x16x32_bf16(ahi, blo, acc[t], 0, 0, 0);
                    acc[t] = __builtin_amdgcn_mfma_f32_16x16x32_bf16(ahi, bhi, acc[t], 0, 0, 0);
                }
            }
        }

        // dump C fragments to LDS (D: col=lane&15, row=lq*4+reg)
        #pragma unroll
        for (int t = 0; t < 4; ++t) {
            int col = gpair*64 + (t>>1)*32 + (t&1)*16 + ln15;
            int rb  = mhalf*16 + lq*4;
            #pragma unroll
            for (int r = 0; r < 4; ++r)
                Csh[rb + r][col] = acc[t][r];
        }
        __syncthreads();

        if (em < SP) {
            size_t gb = ((size_t)t_in*SP + em)*2048 + (size_t)d*1024 + j0 + ej4;
            float4 gi4 = *(const float4*)&G[gb];
            float4 gf4 = *(const float4*)&G[gb + 256];
            float4 gg4 = *(const float4*)&G[gb + 512];
            float4 go4 = *(const float4*)&G[gb + 768];
            float hv[4];
            #pragma unroll
            for (int e = 0; e < 4; ++e) {
                float gi = Csh[emloc][     ej4+e] + (&gi4.x)[e];
                float gf = Csh[emloc][32 + ej4+e] + (&gf4.x)[e];
                float gg = Csh[emloc][64 + ej4+e] + (&gg4.x)[e];
                float go = Csh[emloc][96 + ej4+e] + (&go4.x)[e];
                float cn = sigmoidf_(gf)*creg[e] + sigmoidf_(gi)*tanhf(gg);
                creg[e] = cn;
                hv[e] = sigmoidf_(go)*tanhf(cn);
            }
            size_t cbase = ((size_t)d*SP + em)*HD + j0 + ej4;
            floatx4 ho = (floatx4){hv[0], hv[1], hv[2], hv[3]};
            store_f4_llc(&hbuf_out[cbase], ho);          // LLC-coherent h store
            // packed x_out write (normal cached; consumed after kernel end)
            const int colg = d*HD + j0 + ej4;
            size_t xb = ((size_t)t_in*SP + em)*1024 + (size_t)(colg >> 3)*16 + (colg & 7);
            ushortx4 xh, xl;
            #pragma unroll
            for (int e = 0; e < 4; ++e) {
                unsigned short hb16 = f2bf(hv[e]);
                xh[e] = hb16;
                xl[e] = f2bf(hv[e] - bf2f(hb16));
            }
            *(ushortx4*)&x_out[xb]     = xh;
            *(ushortx4*)&x_out[xb + 8] = xl;
        }

        if (s < B_ - 1) {
            // drain own h stores to LLC, then group-arrive (8 blocks/group)
            asm volatile("s_waitcnt vmcnt(0)" ::: "memory");
            __syncthreads();
            if (tid == 0) {
                atomicAdd(gbar, 1u);                         // device-scope (LLC)
                const unsigned target = (unsigned)(s + 1) * 8u;
                while (load_u32_llc(gbar) < target)
                    __builtin_amdgcn_s_sleep(2);
            }
            __syncthreads();
        }
    }
}

// ---------------------------------------------------------------------------
// Kernel 4a: scores tile (64x64), RPE analytic.
// ---------------------------------------------------------------------------
__global__ __launch_bounds__(256)
void scores_k(const float* __restrict__ q, const float* __restrict__ k,
              float* __restrict__ P, int g)
{
    const int h = blockIdx.z, bl = blockIdx.y, bg = g*GRP + bl;
    const int q0 = (blockIdx.x / 6) * 64;
    const int k0 = (blockIdx.x % 6) * 64;
    const int tid = threadIdx.x;
    __shared__ float qs[64][68];
    __shared__ float ks[64][68];
    {
        int jr = tid >> 2, c16 = (tid & 3) * 16;
        int qq = q0 + jr; if (qq > SP-1) qq = SP-1;
        int kr = k0 + jr; if (kr > SP-1) kr = SP-1;
        const float* qp = &q[((size_t)bg*SP + qq)*512 + h*64 + c16];
        const float* kp = &k[((size_t)bg*SP + kr)*512 + h*64 + c16];
        #pragma unroll
        for (int u = 0; u < 4; ++u) {
            *(float4*)&qs[jr][c16 + u*4] = *(const float4*)(qp + u*4);
            *(float4*)&ks[jr][c16 + u*4] = *(const float4*)(kp + u*4);
        }
    }
    __syncthreads();
    const int tx = tid & 15, ty = tid >> 4;
    float acc[4][4];
    #pragma unroll
    for (int i = 0; i < 4; ++i)
        #pragma unroll
        for (int j = 0; j < 4; ++j) acc[i][j] = 0.0f;
    for (int d4 = 0; d4 < 64; d4 += 4) {
        float4 a[4], b[4];
        #pragma unroll
        for (int i = 0; i < 4; ++i) a[i] = *(const float4*)&qs[ty + 16*i][d4];
        #pragma unroll
        for (int j = 0; j < 4; ++j) b[j] = *(const float4*)&ks[tx + 16*j][d4];
        #pragma unroll
        for (int i = 0; i < 4; ++i)
            #pragma unroll
            for (int j = 0; j < 4; ++j)
                acc[i][j] += a[i].x*b[j].x + a[i].y*b[j].y + a[i].z*b[j].z + a[i].w*b[j].w;
    }
    #pragma unroll
    for (int i = 0; i < 4; ++i) {
        int qq = q0 + ty + 16*i;
        if (qq >= SP) continue;
        int r0 = 6*qq - 1; if (r0 < 0) r0 = 0;
        int r1 = 6*qq + 7; if (r1 > SLEN-1) r1 = SLEN-1;
        size_t rowb = ((size_t)(h*GRP + bl)*SP + qq) * PSTR;
        #pragma unroll
        for (int j = 0; j < 4; ++j) {
            int kk = k0 + tx + 16*j;
            if (kk >= SP) continue;
            int c0 = 6*kk - 1; if (c0 < 0) c0 = 0;
            int c1 = 6*kk + 7;
            int dd1 = c1 - r0; if (dd1 < 0) dd1 = -dd1;
            int dd2 = r1 - c0; if (dd2 < 0) dd2 = -dd2;
            int den = dd1 > dd2 ? dd1 : dd2;
            P[rowb + kk] = (acc[i][j] * 0.125f) * 2047.0f / (float)den;
        }
    }
}

// ---------------------------------------------------------------------------
// Kernel 4b: row softmax in place.
// ---------------------------------------------------------------------------
__global__ __launch_bounds__(256)
void softmax_k(float* __restrict__ P)
{
    const int tid = threadIdx.x;
    const int row = blockIdx.x * 4 + (tid >> 6);
    const int lane = tid & 63;
    float* rp = P + (size_t)row * PSTR;
    float v[6];
    float m = -1e30f;
    #pragma unroll
    for (int i = 0; i < 6; ++i) {
        int col = lane + 64*i;
        v[i] = (col < SP) ? rp[col] : -1e30f;
        m = fmaxf(m, v[i]);
    }
    #pragma unroll
    for (int o = 1; o < 64; o <<= 1) m = fmaxf(m, __shfl_xor(m, o, 64));
    float s = 0.0f;
    #pragma unroll
    for (int i = 0; i < 6; ++i) {
        v[i] = expf(v[i] - m);
        s += v[i];
    }
    #pragma unroll
    for (int o = 1; o < 64; o <<= 1) s += __shfl_xor(s, o, 64);
    float inv = 1.0f / s;
    #pragma unroll
    for (int i = 0; i < 6; ++i) {
        int col = lane + 64*i;
        if (col < SP) rp[col] = v[i] * inv;
    }
}

// ---------------------------------------------------------------------------
// Kernel 4c: out = relu(P @ V), K=SP in 6x64 chunks. cat written PACKED.
// ---------------------------------------------------------------------------
__global__ __launch_bounds__(256)
void pv_k(const float* __restrict__ P, const float* __restrict__ v,
          unsigned short* __restrict__ catp, int g)
{
    const int h = blockIdx.z, bl = blockIdx.y, bg = g*GRP + bl;
    const int q0 = blockIdx.x * 64;
    const int tid = threadIdx.x;
    __shared__ float ps[64][68];
    __shared__ float vs[64][68];
    const int tx = tid & 15, ty = tid >> 4;
    float acc[4][4];
    #pragma unroll
    for (int i = 0; i < 4; ++i)
        #pragma unroll
        for (int j = 0; j < 4; ++j) acc[i][j] = 0.0f;

    for (int kc = 0; kc < 6; ++kc) {
        const int kk0 = kc * 64;
        {
            int jr = tid >> 2, c16 = (tid & 3) * 16;
            int qq = q0 + jr; if (qq > SP-1) qq = SP-1;
            const float* pp = P + ((size_t)(h*GRP + bl)*SP + qq)*PSTR + kk0 + c16;
            #pragma unroll
            for (int u = 0; u < 4; ++u) {
                float4 w = *(const float4*)(pp + u*4);
                int klb = c16 + u*4;
                float vals[4] = {w.x, w.y, w.z, w.w};
                #pragma unroll
                for (int e = 0; e < 4; ++e)
                    ps[klb + e][jr] = (kk0 + klb + e < SP) ? vals[e] : 0.0f;
            }
        }
        {
            int jr = tid >> 2, c16 = (tid & 3) * 16;
            int kr = kk0 + jr; if (kr > SP-1) kr = SP-1;
            const float* vp = &v[((size_t)bg*SP + kr)*512 + h*64 + c16];
            #pragma unroll
            for (int u = 0; u < 4; ++u)
                *(float4*)&vs[jr][c16 + u*4] = *(const float4*)(vp + u*4);
        }
        __syncthreads();
        for (int kk = 0; kk < 64; ++kk) {
            float4 a4 = *(const float4*)&ps[kk][ty*4];
            float4 b4 = *(const float4*)&vs[kk][tx*4];
            float av[4] = {a4.x, a4.y, a4.z, a4.w};
            float bv[4] = {b4.x, b4.y, b4.z, b4.w};
            #pragma unroll
            for (int i = 0; i < 4; ++i)
                #pragma unroll
                for (int j = 0; j < 4; ++j)
                    acc[i][j] += av[i] * bv[j];
        }
        __syncthreads();
    }
    #pragma unroll
    for (int i = 0; i < 4; ++i) {
        int qq = q0 + ty*4 + i;
        if (qq >= SP) continue;
        float r[4];
        r[0] = fmaxf(acc[i][0], 0.0f);
        r[1] = fmaxf(acc[i][1], 0.0f);
        r[2] = fmaxf(acc[i][2], 0.0f);
        r[3] = fmaxf(acc[i][3], 0.0f);
        const int colg = h*64 + tx*4;
        size_t xb = ((size_t)bg*SP + qq)*1024 + (size_t)(colg >> 3)*16 + (colg & 7);
        ushortx4 xh, xl;
        #pragma unroll
        for (int e = 0; e < 4; ++e) {
            unsigned short hb16 = f2bf(r[e]);
            xh[e] = hb16;
            xl[e] = f2bf(r[e] - bf2f(hb16));
        }
        *(ushortx4*)&catp[xb]     = xh;
        *(ushortx4*)&catp[xb + 8] = xl;
    }
}

// ---------------------------------------------------------------------------
extern "C" void kernel_launch(void* const* d_in, const int* in_sizes, int n_in,
                              void* d_out, int out_size, void* d_ws, size_t ws_size,
                              hipStream_t stream)
{
    (void)in_sizes; (void)n_in; (void)out_size; (void)ws_size;
    const float* in    = (const float*)d_in[0];
    const float* cw    = (const float*)d_in[1];
    const float* gamma = (const float*)d_in[2];
    const float* beta  = (const float*)d_in[3];
    const float* Wih0  = (const float*)d_in[4];
    const float* Whh0  = (const float*)d_in[5];
    const float* b0    = (const float*)d_in[6];
    const float* Wih1  = (const float*)d_in[7];
    const float* Whh1  = (const float*)d_in[8];
    const float* b1    = (const float*)d_in[9];
    const float* Qw    = (const float*)d_in[10];
    const float* Qb    = (const float*)d_in[11];
    const float* Kw    = (const float*)d_in[12];
    const float* Kb    = (const float*)d_in[13];
    const float* Vw    = (const float*)d_in[14];
    const float* Vb    = (const float*)d_in[15];
    const float* mhw   = (const float*)d_in[16];
    const float* mhb   = (const float*)d_in[17];
    float* out = (float*)d_out;

    // workspace arena (floats). Same region map as before.
    float* x0 = (float*)d_ws;                                   //  2,793,472 f
    float* G  = x0 + (size_t)RTOT*NF;                           // 22,347,776 f
    float* x1 = G  + (size_t)RTOT*2048;                         //  5,586,944 f
    float* x2 = x1 + (size_t)RTOT*512;                          //  5,586,944 f
    float* hb = x2 + (size_t)RTOT*512;                          //    349,184 f
    float* cb = hb + (size_t)2*2*SP*HD;                         //    174,592 f (c in regs; holds barriers)

    float* qbuf = G;
    float* kbuf = G + (size_t)RTOT*512;
    float* vbuf = G + (size_t)2*RTOT*512;
    float* P    = G + (size_t)3*RTOT*512;
    unsigned* bar = (unsigned*)cb;          // 22 groups x 64 u32 (256B stride)

    // ---- packed-buffer aliases (each placed in a region dead at time of use) ----
    unsigned short* x0p = (unsigned short*)x0;
    unsigned short* whh1_hi = (unsigned short*)x0;                         // after gemm1
    unsigned short* whh1_lo = whh1_hi + (size_t)524288;
    unsigned short* wih0_p  = (unsigned short*)x2;
    unsigned short* wih1_p  = wih0_p + (size_t)1048576;
    unsigned short* whh0_hi = wih1_p + (size_t)2097152;
    unsigned short* whh0_lo = whh0_hi + (size_t)524288;
    unsigned short* x1p  = (unsigned short*)x1;
    unsigned short* catp = (unsigned short*)x1;
    unsigned short* x2p = (unsigned short*)x2;
    float* gslack = P + (size_t)NH_*GRP*SP*PSTR;
    unsigned short* qw_p = (unsigned short*)gslack;
    unsigned short* kw_p = qw_p + (size_t)524288;
    unsigned short* vw_p = kw_p + (size_t)524288;
    unsigned short* mw_p = vw_p + (size_t)524288;

    #define PACKGRID(n) dim3(((n) + 255) / 256)

    // 1. conv+bn+relu+pool -> x0p (packed)
    conv_pool_k<<<dim3(22, B_), 256, 0, stream>>>(in, cw, gamma, beta, x0p);
    // 2. pack Wih0 (octet) into x2 region
    pack8_k<<<PACKGRID(65536), 256, 0, stream>>>(Wih0, wih0_p, 65536);
    // 3. layer-1 input gates: G = x0 @ Wih0^T + b0   (K=256)
    gemm_bf_k<0><<<dim3(16, 86), 256, 0, stream>>>(x0p, wih0_p, b0, G, RTOT, 2048, 256);
    // 4. pack Whh0 (x2 tail), Whh1 (x0 region, dead after gemm1), Wih1 (x2)
    pack4_k<<<PACKGRID(131072), 256, 0, stream>>>(Whh0, whh0_hi, whh0_lo, 131072);
    pack4_k<<<PACKGRID(131072), 256, 0, stream>>>(Whh1, whh1_hi, whh1_lo, 131072);
    pack8_k<<<PACKGRID(131072), 256, 0, stream>>>(Wih1, wih1_p, 131072);
    // 5. layer-1 scan -> x1p (persistent, group-local LLC barriers)
    hipMemsetAsync(bar, 0, 22*64*sizeof(unsigned), stream);
    {
        const float* a0 = G; const unsigned short* a1 = whh0_hi; const unsigned short* a2 = whh0_lo;
        float* a3 = hb; unsigned short* a4 = x1p; unsigned* a5 = bar;
        void* kargs[] = {&a0, &a1, &a2, &a3, &a4, &a5};
        hipLaunchCooperativeKernel((void*)lstm_scan_k, dim3(8, 11, 2), dim3(256, 1, 1), kargs, 0, stream);
    }
    // 6. layer-2 input gates: G = x1 @ Wih1^T + b1   (K=512)
    gemm_bf_k<0><<<dim3(16, 86), 256, 0, stream>>>(x1p, wih1_p, b1, G, RTOT, 2048, 512);
    // 7. layer-2 scan -> x2p
    hipMemsetAsync(bar, 0, 22*64*sizeof(unsigned), stream);
    {
        const float* a0 = G; const unsigned short* a1 = whh1_hi; const unsigned short* a2 = whh1_lo;
        float* a3 = hb; unsigned short* a4 = x2p; unsigned* a5 = bar;
        void* kargs[] = {&a0, &a1, &a2, &a3, &a4, &a5};
        hipLaunchCooperativeKernel((void*)lstm_scan_k, dim3(8, 11, 2), dim3(256, 1, 1), kargs, 0, stream);
    }
    // 8. pack QKV/mh weights into G tail slack (G-as-gates dead)
    pack8_k<<<PACKGRID(32768), 256, 0, stream>>>(Qw,  qw_p, 32768);
    pack8_k<<<PACKGRID(32768), 256, 0, stream>>>(Kw,  kw_p, 32768);
    pack8_k<<<PACKGRID(32768), 256, 0, stream>>>(Vw,  vw_p, 32768);
    pack8_k<<<PACKGRID(32768), 256, 0, stream>>>(mhw, mw_p, 32768);
    // 9. Q/K/V projections (fp32 outputs into G region)
    gemm_bf_k<0><<<dim3(4, 86), 256, 0, stream>>>(x2p, qw_p, Qb, qbuf, RTOT, 512, 512);
    gemm_bf_k<0><<<dim3(4, 86), 256, 0, stream>>>(x2p, kw_p, Kb, kbuf, RTOT, 512, 512);
    gemm_bf_k<0><<<dim3(4, 86), 256, 0, stream>>>(x2p, vw_p, Vb, vbuf, RTOT, 512, 512);
    // 10. attention in GRP-batch groups; pv writes catp (x1 region, packed)
    for (int g = 0; g < B_/GRP; ++g) {
        scores_k <<<dim3(36, GRP, NH_), 256, 0, stream>>>(qbuf, kbuf, P, g);
        softmax_k<<<dim3(NH_*GRP*SP/4), 256, 0, stream>>>(P);
        pv_k     <<<dim3(6, GRP, NH_), 256, 0, stream>>>(P, vbuf, catp, g);
    }
    // 11. final linear + relu
    gemm_bf_k<1><<<dim3(4, 86), 256, 0, stream>>>(catp, mw_p, mhb, out, RTOT, 512, 512);
    #undef PACKGRID
}